// Round 4
// baseline (669.694 us; speedup 1.0000x reference)
//
#include <hip/hip_runtime.h>
#include <hip/hip_bf16.h>

typedef unsigned short u16;
typedef unsigned int   u32;
typedef __attribute__((ext_vector_type(8))) short short8;
typedef __attribute__((ext_vector_type(4))) float float4v;

// ---------- helpers ----------
__device__ __forceinline__ float bf2f(u16 u){ union{u32 i; float f;} c; c.i = ((u32)u) << 16; return c.f; }
__device__ __forceinline__ float bflo(u32 u){ union{u32 i; float f;} c; c.i = u << 16; return c.f; }
__device__ __forceinline__ float bfhi(u32 u){ union{u32 i; float f;} c; c.i = u & 0xFFFF0000u; return c.f; }
__device__ __forceinline__ u16 f2bf(float f){
  union{float f; u32 i;} c; c.f = f; u32 x = c.i;
  return (u16)((x + 0x7FFFu + ((x >> 16) & 1u)) >> 16);   // RNE
}
// packed f32x2 -> bf16x2, RNE (v_cvt_pk_bf16_f32)
__device__ __forceinline__ u32 pack2(float a, float b){
  union { __hip_bfloat162 h; u32 u; } c;
  c.h = __float22bfloat162_rn(float2{a, b});
  return c.u;
}

__device__ __forceinline__ void async16(const void* g, void* l){
  __builtin_amdgcn_global_load_lds((const __attribute__((address_space(1))) void*)g,
                                   (__attribute__((address_space(3))) void*)l, 16, 0, 0);
}

// ---------- prep: feats fp32 -> bf16 (done ONCE) ----------
__global__ void __launch_bounds__(256) conv_bf16(const float* __restrict__ src, u16* __restrict__ dst, int n8)
{
  int t = blockIdx.x * 256 + threadIdx.x;
  int stride = gridDim.x * 256;
  for (int i = t; i < n8; i += stride) {
    float4 a = ((const float4*)src)[2 * i];
    float4 b = ((const float4*)src)[2 * i + 1];
    uint4 o = { pack2(a.x, a.y), pack2(a.z, a.w), pack2(b.x, b.y), pack2(b.z, b.w) };
    ((uint4*)dst)[i] = o;
  }
}

// ---------- prep: QHB rows 0-1535 = [wq_w; wk_w] bf16; bias[2304] fp32 (0 beyond 1536) ----------
__global__ void prep_qkw(const float* __restrict__ wq, const float* __restrict__ wk,
                         const float* __restrict__ wqb, const float* __restrict__ wkb,
                         u16* __restrict__ QHB, float* __restrict__ biasQH)
{
  int t = blockIdx.x * 256 + threadIdx.x;
  int stride = gridDim.x * 256;
  for (int i = t; i < 294912; i += stride) {
    float4 v = (i < 147456) ? ((const float4*)wq)[i] : ((const float4*)wk)[i - 147456];
    ushort4 o; o.x = f2bf(v.x); o.y = f2bf(v.y); o.z = f2bf(v.z); o.w = f2bf(v.w);
    ((ushort4*)QHB)[i] = o;
  }
  if (t < 768) biasQH[t] = wqb[t];
  else if (t < 1536) biasQH[t] = wkb[t - 768];
  else if (t < 2304) biasQH[t] = 0.f;
}

// gcn_w[l][d][o] -> l==0: QHB rows 1536+o ; l==1: gcnT1[o][d]   (fp32 -> bf16, transposed)
__global__ void prep_gcnT(const float* __restrict__ gcn, u16* __restrict__ QHB, u16* __restrict__ gcnT1)
{
  __shared__ float tile[32][33];
  int l = blockIdx.z;
  int d0 = blockIdx.y * 32, o0 = blockIdx.x * 32;
  int tx = threadIdx.x, ty = threadIdx.y;           // 32 x 8
  const float* src = gcn + (size_t)l * 589824;
  u16* dst = (l == 0) ? (QHB + (size_t)1536 * 768) : gcnT1;
  for (int i = 0; i < 32; i += 8) tile[ty + i][tx] = src[(size_t)(d0 + ty + i) * 768 + o0 + tx];
  __syncthreads();
  for (int i = 0; i < 32; i += 8) dst[(size_t)(o0 + ty + i) * 768 + d0 + tx] = f2bf(tile[tx][ty + i]);
}

// ---------- main GEMM: C[m][n] = sum_k A[m][k]*B[n][k] + bias[n] ----------
// 256x256 tile, BK=64, 8 waves (2Mx4N), double-buffered LDS (128 KiB), counted
// vmcnt(8) pipeline: next tile's 8 global_load_lds stay IN FLIGHT across both
// barriers (T3+T4); s_setprio(1) around the MFMA cluster (T5). Chunk-XOR LDS
// swizzle (verified conflict-free): lane fetches source chunk (l&7)^(l>>3) into
// linear LDS slot l&7, read at slot (ks*4+quad)^(l15&7).
__global__ void __launch_bounds__(512, 2) gemm_bt(const u16* __restrict__ A, const u16* __restrict__ Bw,
                                                  const float* __restrict__ bias, u16* __restrict__ C,
                                                  int M, int N, int K)
{
  __shared__ __attribute__((aligned(16))) u16 As[2][256 * 64];
  __shared__ __attribute__((aligned(16))) u16 Bs[2][256 * 64];
  int tid = threadIdx.x, lane = tid & 63, wid = tid >> 6;   // 8 waves
  int wm = wid >> 2, wn = wid & 3;                          // 2 x 4
  size_t m0 = (size_t)blockIdx.x * 256, n0 = (size_t)blockIdx.y * 256;

  float4v acc[8][4];
#pragma unroll
  for (int r = 0; r < 8; r++)
#pragma unroll
    for (int c = 0; c < 4; c++) acc[r][c] = (float4v){0.f, 0.f, 0.f, 0.f};

  // staging: wave w rows [32w, 32w+32), call j covers 8 rows; lane l -> row +8j+(l>>3),
  // source k-chunk (l&7)^(l>>3); LDS dest = wave-uniform base + lane*16 (linear).
  int srow8  = lane >> 3;
  int schunk = (lane & 7) ^ srow8;
  const u16* gA[4]; const u16* gB[4]; int ldsO[4];
#pragma unroll
  for (int j = 0; j < 4; j++) {
    int r = 32 * wid + 8 * j + srow8;
    size_t rA = m0 + r; if (rA >= (size_t)M) rA = M - 1;    // M-edge clamp (GC=64 fallback)
    gA[j] = A  + rA * (size_t)K + schunk * 8;
    gB[j] = Bw + (n0 + r) * (size_t)K + schunk * 8;
    ldsO[j] = (32 * wid + 8 * j) * 64;                      // u16 index
  }

  int l15 = lane & 15, quad = lane >> 4;
  int l7 = l15 & 7;
  int nk = K >> 6;                                          // 12 for K=768

  // prologue: stage tile 0 into buf 0
#pragma unroll
  for (int j = 0; j < 4; j++) {
    async16(gA[j], &As[0][ldsO[j]]);
    async16(gB[j], &Bs[0][ldsO[j]]);
  }

  for (int t = 0; t < nk; ++t) {
    int cur = t & 1, nxt = cur ^ 1;
    if (t + 1 < nk) {
      int kt = (t + 1) << 6;
#pragma unroll
      for (int j = 0; j < 4; j++) {
        async16(gA[j] + kt, &As[nxt][ldsO[j]]);
        async16(gB[j] + kt, &Bs[nxt][ldsO[j]]);
      }
      asm volatile("s_waitcnt vmcnt(8)" ::: "memory");      // tile t done; t+1 in flight
    } else {
      asm volatile("s_waitcnt vmcnt(0)" ::: "memory");      // last tile drain
    }
    __builtin_amdgcn_s_barrier();
    __builtin_amdgcn_sched_barrier(0);                      // no ds_read hoists above barrier

#pragma unroll
    for (int ks = 0; ks < 2; ks++) {
      int so = ((quad ^ l7) ^ (ks << 2)) * 8;
      short8 bfr[4];
#pragma unroll
      for (int c = 0; c < 4; c++)
        bfr[c] = *(const short8*)&Bs[cur][(wn * 64 + c * 16 + l15) * 64 + so];
      __builtin_amdgcn_s_setprio(1);
#pragma unroll
      for (int r = 0; r < 8; r++) {
        short8 a = *(const short8*)&As[cur][(wm * 128 + r * 16 + l15) * 64 + so];
#pragma unroll
        for (int c = 0; c < 4; c++)
          acc[r][c] = __builtin_amdgcn_mfma_f32_16x16x32_bf16(a, bfr[c], acc[r][c], 0, 0, 0);
      }
      __builtin_amdgcn_s_setprio(0);
    }
    __builtin_amdgcn_sched_barrier(0);                      // all reads of buf[cur] done below barrier
    __builtin_amdgcn_s_barrier();                           // before t+2 overwrites buf[cur]
  }

  int quad4 = quad * 4;
  for (int c = 0; c < 4; c++) {
    int n = (int)n0 + wn * 64 + c * 16 + l15;
    float bv = bias ? bias[n] : 0.f;
    for (int r = 0; r < 8; r++) {
      size_t mbase = m0 + wm * 128 + r * 16 + quad4;
      for (int t = 0; t < 4; t++)
        if (mbase + t < (size_t)M)
          C[(mbase + t) * (size_t)N + n] = f2bf(acc[r][c][t] + bv);
    }
  }
}

// ================= fused per-graph adjacency kernels =================
// QH rows (stride 2304): [0,768)=Q, [768,1536)=K, [1536,2304)=H1.
// L1: S=Q.K^T per-wave direct-from-global MFMA (no barriers) -> rowsum via shfl+LDS atomics
//     -> adj bf16 (LDS + global) -> X1 = relu(LN(adj@H1)) via chunked HT transpose.
// L2: load adj -> relu(LN(adj@H2)) -> column mean only.
// Stage 2 chunk loop: HT double-buffered (ONE barrier per chunk) + depth-1
// register prefetch of the next H chunk so its HBM latency hides under compute.

template<int NP>
__global__ void __launch_bounds__(512) fused_l1(const u16* __restrict__ QH,
                                                const float* __restrict__ lng, const float* __restrict__ lnb,
                                                u16* __restrict__ adjG, u16* __restrict__ X, int n)
{
  constexpr int ST = 72;
  constexpr int TPW = (NP == 64) ? 2 : 1;
  __shared__ __attribute__((aligned(16))) u16 adjb[NP * ST];
  __shared__ __attribute__((aligned(16))) u16 HT[2][64 * ST];
  __shared__ float rsum[NP];
  __shared__ float stats[NP][2];
  __shared__ float bc[NP][2];
  __shared__ float lg[768], lb[768];

  int g = blockIdx.x;
  int tid = threadIdx.x, lane = tid & 63, w = tid >> 6;
  int l15 = lane & 15, quad = lane >> 4;

  for (int i = tid; i < 768; i += 512) { lg[i] = lng[i]; lb[i] = lnb[i]; }
  if (tid < NP) { rsum[tid] = 0.f; stats[tid][0] = 0.f; stats[tid][1] = 0.f; }
  __syncthreads();

  // ---- stage 1: S = Q @ K^T, per-wave, no LDS/barriers ----
  int mt, nt0; bool s_act;
  if (NP == 64) { mt = w & 3; nt0 = (w >> 2) * 2; s_act = true; }
  else          { mt = w & 1; nt0 = w >> 1;       s_act = (w < 4); }

  int rowA = mt * 16 + l15;
  bool aok = rowA < n;
  const u16* pA  = QH + ((size_t)g * n + rowA) * 2304 + quad * 8;
  int rowB0 = (nt0) * 16 + l15, rowB1 = (nt0 + TPW - 1) * 16 + l15;
  bool b0ok = rowB0 < n, b1ok = rowB1 < n;
  const u16* pB0 = QH + ((size_t)g * n + rowB0) * 2304 + 768 + quad * 8;
  const u16* pB1 = QH + ((size_t)g * n + rowB1) * 2304 + 768 + quad * 8;

  float4v sacc[TPW];
  for (int j = 0; j < TPW; j++) sacc[j] = (float4v){0.f, 0.f, 0.f, 0.f};

  if (s_act) {
    for (int kt = 0; kt < 768; kt += 32) {
      uint4 av = {0,0,0,0}, bv0 = {0,0,0,0}, bv1 = {0,0,0,0};
      if (aok)  av  = *(const uint4*)(pA + kt);
      if (b0ok) bv0 = *(const uint4*)(pB0 + kt);
      if (TPW == 2 && b1ok) bv1 = *(const uint4*)(pB1 + kt);
      short8 a = *(short8*)&av;
      sacc[0] = __builtin_amdgcn_mfma_f32_16x16x32_bf16(a, *(short8*)&bv0, sacc[0], 0, 0, 0);
      if (TPW == 2)
        sacc[1] = __builtin_amdgcn_mfma_f32_16x16x32_bf16(a, *(short8*)&bv1, sacc[1], 0, 0, 0);
    }
    // partial row sums of S^2 (reduce over the 16 cols held across l15 lanes)
    for (int t = 0; t < 4; t++) {
      float s = 0.f;
      for (int j = 0; j < TPW; j++) { float v = sacc[j][t]; s += v * v; }
      s += __shfl_xor(s, 1); s += __shfl_xor(s, 2); s += __shfl_xor(s, 4); s += __shfl_xor(s, 8);
      if (l15 == 0) atomicAdd(&rsum[mt * 16 + quad * 4 + t], s);
    }
  }
  __syncthreads();
  if (tid < NP) rsum[tid] = 1.0f / fmaxf(rsum[tid], 1e-12f);
  __syncthreads();
  if (s_act) {
    u16* gadj = adjG + (size_t)g * NP * NP;
    for (int j = 0; j < TPW; j++)
      for (int t = 0; t < 4; t++) {
        int row = mt * 16 + quad * 4 + t, col = (nt0 + j) * 16 + l15;
        float v = sacc[j][t];
        u16 b = f2bf(v * v * rsum[row]);
        adjb[row * ST + col] = b;
        gadj[row * NP + col] = b;
      }
  }
  __syncthreads();

  // ---- stage 2: X = adj @ H1, 12 chunks of 64 d-cols ----
  int m2, nt20;
  if (NP == 64) { m2 = w & 3; nt20 = (w >> 2) * 2; }
  else          { m2 = w & 1; nt20 = w >> 1; }

  float4v xacc[12][TPW];
#pragma unroll
  for (int ch = 0; ch < 12; ch++) for (int j = 0; j < TPW; j++) xacc[ch][j] = (float4v){0.f,0.f,0.f,0.f};

  // transpose mapping: hj = node (fast across lanes -> banks spread), hseg = d-octet
  int hj  = tid & (NP - 1);
  int hseg= (NP == 64) ? w : ((tid >> 5) & 7);
  bool hact = (NP == 64) ? true : (tid < NP * 8);
  const u16* hbase = QH + ((size_t)g * n + hj) * 2304 + 1536 + hseg * 8;

  uint4 hcur = {0,0,0,0};
  if (hact && hj < n) hcur = *(const uint4*)(hbase);

#pragma unroll
  for (int ch = 0; ch < 12; ch++) {
    uint4 hnext = {0,0,0,0};
    if (ch < 11 && hact && hj < n) hnext = *(const uint4*)(hbase + (ch + 1) * 64);
    u16* htb = HT[ch & 1];
    if (hact) {
      const u16* ep = (const u16*)&hcur;
      for (int i = 0; i < 8; i++) htb[(hseg * 8 + i) * ST + hj] = ep[i];
    }
    __syncthreads();
    for (int k = 0; k < NP / 32; k++) {
      short8 a = *(const short8*)&adjb[(m2 * 16 + l15) * ST + k * 32 + quad * 8];
      for (int j = 0; j < TPW; j++) {
        short8 b = *(const short8*)&htb[((nt20 + j) * 16 + l15) * ST + k * 32 + quad * 8];
        xacc[ch][j] = __builtin_amdgcn_mfma_f32_16x16x32_bf16(a, b, xacc[ch][j], 0, 0, 0);
      }
    }
    hcur = hnext;
  }

  // ---- LN stats ----
  float ssum[4] = {0,0,0,0}, ssq[4] = {0,0,0,0};
#pragma unroll
  for (int ch = 0; ch < 12; ch++)
    for (int j = 0; j < TPW; j++)
      for (int t = 0; t < 4; t++) { float v = xacc[ch][j][t]; ssum[t] += v; ssq[t] += v * v; }
  for (int m = 1; m <= 8; m <<= 1)
    for (int t = 0; t < 4; t++) { ssum[t] += __shfl_xor(ssum[t], m); ssq[t] += __shfl_xor(ssq[t], m); }
  if (l15 == 0)
    for (int t = 0; t < 4; t++) {
      atomicAdd(&stats[m2 * 16 + quad * 4 + t][0], ssum[t]);
      atomicAdd(&stats[m2 * 16 + quad * 4 + t][1], ssq[t]);
    }
  __syncthreads();
  if (tid < NP) {
    float mu = stats[tid][0] * (1.f / 768.f);
    float var = stats[tid][1] * (1.f / 768.f) - mu * mu;
    bc[tid][0] = mu; bc[tid][1] = rsqrtf(fmaxf(var, 0.f) + 1e-5f);
  }
  __syncthreads();

  // ---- LN + relu + write X ----
#pragma unroll
  for (int ch = 0; ch < 12; ch++)
    for (int j = 0; j < TPW; j++)
      for (int t = 0; t < 4; t++) {
        int row = m2 * 16 + quad * 4 + t;
        if (row < n) {
          int d = ch * 64 + (nt20 + j) * 16 + l15;
          float v = fmaxf((xacc[ch][j][t] - bc[row][0]) * bc[row][1] * lg[d] + lb[d], 0.f);
          X[((size_t)g * n + row) * 768 + d] = f2bf(v);
        }
      }
}

template<int NP>
__global__ void __launch_bounds__(512) fused_l2(const u16* __restrict__ adjG, const u16* __restrict__ H,
                                                const float* __restrict__ lng, const float* __restrict__ lnb,
                                                u16* __restrict__ Xmean, int n, float inv)
{
  constexpr int ST = 72;
  constexpr int TPW = (NP == 64) ? 2 : 1;
  __shared__ __attribute__((aligned(16))) u16 adjb[NP * ST];
  __shared__ __attribute__((aligned(16))) u16 HT[2][64 * ST];
  __shared__ float stats[NP][2];
  __shared__ float bc[NP][2];
  __shared__ float colsum[768];
  __shared__ float lg[768], lb[768];

  int g = blockIdx.x;
  int tid = threadIdx.x, lane = tid & 63, w = tid >> 6;
  int l15 = lane & 15, quad = lane >> 4;

  for (int i = tid; i < 768; i += 512) { lg[i] = lng[i]; lb[i] = lnb[i]; colsum[i] = 0.f; }
  if (tid < NP) { stats[tid][0] = 0.f; stats[tid][1] = 0.f; }
  if (tid * 8 < NP * NP) {
    int row = (tid * 8) / NP, c0 = (tid * 8) % NP;
    uint4 v = *(const uint4*)(adjG + (size_t)g * NP * NP + row * NP + c0);
    *(uint4*)&adjb[row * ST + c0] = v;
  }

  int m2, nt20;
  if (NP == 64) { m2 = w & 3; nt20 = (w >> 2) * 2; }
  else          { m2 = w & 1; nt20 = w >> 1; }

  float4v xacc[12][TPW];
#pragma unroll
  for (int ch = 0; ch < 12; ch++) for (int j = 0; j < TPW; j++) xacc[ch][j] = (float4v){0.f,0.f,0.f,0.f};

  int hj  = tid & (NP - 1);
  int hseg= (NP == 64) ? w : ((tid >> 5) & 7);
  bool hact = (NP == 64) ? true : (tid < NP * 8);
  const u16* hbase = H + ((size_t)g * n + hj) * 768 + hseg * 8;

  uint4 hcur = {0,0,0,0};
  if (hact && hj < n) hcur = *(const uint4*)(hbase);

  __syncthreads();   // adjb + colsum/stats init visible

#pragma unroll
  for (int ch = 0; ch < 12; ch++) {
    uint4 hnext = {0,0,0,0};
    if (ch < 11 && hact && hj < n) hnext = *(const uint4*)(hbase + (ch + 1) * 64);
    u16* htb = HT[ch & 1];
    if (hact) {
      const u16* ep = (const u16*)&hcur;
      for (int i = 0; i < 8; i++) htb[(hseg * 8 + i) * ST + hj] = ep[i];
    }
    __syncthreads();
    for (int k = 0; k < NP / 32; k++) {
      short8 a = *(const short8*)&adjb[(m2 * 16 + l15) * ST + k * 32 + quad * 8];
      for (int j = 0; j < TPW; j++) {
        short8 b = *(const short8*)&htb[((nt20 + j) * 16 + l15) * ST + k * 32 + quad * 8];
        xacc[ch][j] = __builtin_amdgcn_mfma_f32_16x16x32_bf16(a, b, xacc[ch][j], 0, 0, 0);
      }
    }
    hcur = hnext;
  }

  float ssum[4] = {0,0,0,0}, ssq[4] = {0,0,0,0};
#pragma unroll
  for (int ch = 0; ch < 12; ch++)
    for (int j = 0; j < TPW; j++)
      for (int t = 0; t < 4; t++) { float v = xacc[ch][j][t]; ssum[t] += v; ssq[t] += v * v; }
  for (int m = 1; m <= 8; m <<= 1)
    for (int t = 0; t < 4; t++) { ssum[t] += __shfl_xor(ssum[t], m); ssq[t] += __shfl_xor(ssq[t], m); }
  if (l15 == 0)
    for (int t = 0; t < 4; t++) {
      atomicAdd(&stats[m2 * 16 + quad * 4 + t][0], ssum[t]);
      atomicAdd(&stats[m2 * 16 + quad * 4 + t][1], ssq[t]);
    }
  __syncthreads();
  if (tid < NP) {
    float mu = stats[tid][0] * (1.f / 768.f);
    float var = stats[tid][1] * (1.f / 768.f) - mu * mu;
    bc[tid][0] = mu; bc[tid][1] = rsqrtf(fmaxf(var, 0.f) + 1e-5f);
  }
  __syncthreads();

#pragma unroll
  for (int ch = 0; ch < 12; ch++)
    for (int j = 0; j < TPW; j++)
      for (int t = 0; t < 4; t++) {
        int row = m2 * 16 + quad * 4 + t;
        int d = ch * 64 + (nt20 + j) * 16 + l15;
        float v = fmaxf((xacc[ch][j][t] - bc[row][0]) * bc[row][1] * lg[d] + lb[d], 0.f);
        float vm = (row < n) ? v : 0.f;
        vm += __shfl_xor(vm, 16);
        vm += __shfl_xor(vm, 32);
        if (quad == 0) atomicAdd(&colsum[d], vm);
      }
  __syncthreads();
  if (tid < 384)
    ((u32*)Xmean)[(size_t)g * 384 + tid] = pack2(colsum[tid * 2] * inv, colsum[tid * 2 + 1] * inv);
}

// ---------- concat: y = [bf2f(Xm) ; fgs] fp32 (in d_out) ----------
__global__ void __launch_bounds__(384) concat_y(const u16* __restrict__ Xm,
                                                const float* __restrict__ fgs, float* __restrict__ yout)
{
  int b = blockIdx.x, tid = threadIdx.x;
  u32 u = ((const u32*)Xm)[(size_t)b * 384 + tid];
  int d0 = tid * 2;
  yout[(size_t)b * 1536 + d0]     = bflo(u);
  yout[(size_t)b * 1536 + d0 + 1] = bfhi(u);
  yout[(size_t)b * 1536 + 768 + d0]     = fgs[(size_t)b * 768 + d0];
  yout[(size_t)b * 1536 + 768 + d0 + 1] = fgs[(size_t)b * 768 + d0 + 1];
}

// ---------- classifier ----------
__global__ void __launch_bounds__(256) fc1_relu(const float* __restrict__ yout,
                                                const float* __restrict__ fc1w, const float* __restrict__ fc1b,
                                                float* __restrict__ h)
{
  int o = blockIdx.x * 4 + (threadIdx.x >> 6);
  int lane = threadIdx.x & 63;
  float acc[16];
  for (int b = 0; b < 16; b++) acc[b] = 0.f;
  const float4* wr = (const float4*)(fc1w + (size_t)o * 1536);
  for (int k4 = lane; k4 < 384; k4 += 64) {
    float4 wv = wr[k4];
    for (int b = 0; b < 16; b++) {
      float4 yv = ((const float4*)(yout + (size_t)b * 1536))[k4];
      acc[b] += wv.x * yv.x + wv.y * yv.y + wv.z * yv.z + wv.w * yv.w;
    }
  }
  for (int m = 1; m <= 32; m <<= 1)
    for (int b = 0; b < 16; b++) acc[b] += __shfl_xor(acc[b], m);
  if (lane < 16) h[(size_t)lane * 768 + o] = fmaxf(acc[lane] + fc1b[o], 0.f);
}

__global__ void __launch_bounds__(256) fc2_out(const float* __restrict__ h,
                                               const float* __restrict__ fc2w, const float* __restrict__ fc2b,
                                               float* __restrict__ logits)
{
  int o = blockIdx.x * 4 + (threadIdx.x >> 6);
  int lane = threadIdx.x & 63;
  float acc[16];
  for (int b = 0; b < 16; b++) acc[b] = 0.f;
  const float4* wr = (const float4*)(fc2w + (size_t)o * 768);
  for (int k4 = lane; k4 < 192; k4 += 64) {
    float4 wv = wr[k4];
    for (int b = 0; b < 16; b++) {
      float4 hv = ((const float4*)(h + (size_t)b * 768))[k4];
      acc[b] += wv.x * hv.x + wv.y * hv.y + wv.z * hv.z + wv.w * hv.w;
    }
  }
  for (int m = 1; m <= 32; m <<= 1)
    for (int b = 0; b < 16; b++) acc[b] += __shfl_xor(acc[b], m);
  if (lane < 16) logits[(size_t)lane * 400 + o] = acc[lane] + fc2b[o];
}

// ---------- launch ----------
extern "C" void kernel_launch(void* const* d_in, const int* in_sizes, int n_in,
                              void* d_out, int out_size, void* d_ws, size_t ws_size,
                              hipStream_t stream) {
  const float* feats = (const float*)d_in[0];
  const float* fgs   = (const float*)d_in[1];
  const float* wq_w  = (const float*)d_in[3];
  const float* wq_b  = (const float*)d_in[4];
  const float* wk_w  = (const float*)d_in[5];
  const float* wk_b  = (const float*)d_in[6];
  const float* gcn_w = (const float*)d_in[7];
  const float* ln_g  = (const float*)d_in[8];
  const float* ln_b  = (const float*)d_in[9];
  const float* fc1_w = (const float*)d_in[10];
  const float* fc1_b = (const float*)d_in[11];
  const float* fc2_w = (const float*)d_in[12];
  const float* fc2_b = (const float*)d_in[13];
  float* out  = (float*)d_out;
  float* yout = out + 16 * 400;               // y region: [16][1536] fp32

  char* ws = (char*)d_ws;
  size_t off = 0;
  auto alloc = [&](size_t b){ size_t r = off; off = (off + b + 255) & ~(size_t)255; return r; };
  // persistent (~50 MB)
  u16*  QHB    = (u16*) (ws + alloc((size_t)2304 * 768 * 2));    // [Wq;Wk;gcn0^T] bf16
  u16*  gcnT1  = (u16*) (ws + alloc((size_t)768 * 768 * 2));
  float* biasQH= (float*)(ws + alloc((size_t)2304 * 4));
  u16*  Abf    = (u16*) (ws + alloc((size_t)25600 * 768 * 2));   // feats pre-converted to bf16
  u16*  Xf     = (u16*) (ws + alloc((size_t)512 * 768 * 2));
  u16*  QHf    = (u16*) (ws + alloc((size_t)512 * 2304 * 2));
  u16*  X1f    = (u16*) (ws + alloc((size_t)512 * 768 * 2));
  u16*  H2f    = (u16*) (ws + alloc((size_t)512 * 768 * 2));
  u16*  adjFb  = (u16*) (ws + alloc((size_t)16 * 32 * 32 * 2));
  u16*  Xm     = (u16*) (ws + alloc((size_t)16 * 768 * 2));
  float* hbuf  = (float*)(ws + alloc((size_t)16 * 768 * 4));
  size_t base = off;

  // per-chunk: QHc [R][2304] + X1c [R][768] + adjGc [GC][64][64] bf16 (H2c aliases QHc)
  auto need = [&](int GC){
    size_t R = (size_t)GC * 50;
    return base + R * 2304 * 2 + 512 + R * 768 * 2 + 512 + (size_t)GC * 64 * 64 * 2 + 512;
  };
  int GC = 64;
  if (need(512) <= ws_size) GC = 512;
  else if (need(256) <= ws_size) GC = 256;
  else if (need(128) <= ws_size) GC = 128;
  int R = GC * 50;
  size_t off2 = base;
  auto alloc2 = [&](size_t b){ size_t r = off2; off2 = (off2 + b + 255) & ~(size_t)255; return r; };
  u16* QHc   = (u16*)(ws + alloc2((size_t)R * 2304 * 2));
  u16* X1c   = (u16*)(ws + alloc2((size_t)R * 768 * 2));
  u16* adjGc = (u16*)(ws + alloc2((size_t)GC * 64 * 64 * 2));
  u16* H2c   = QHc;                      // QH dead after fused_l1

  // prep
  conv_bf16<<<2048, 256, 0, stream>>>(feats, Abf, 25600 * 768 / 8);
  prep_qkw<<<288, 256, 0, stream>>>(wq_w, wk_w, wq_b, wk_b, QHB, biasQH);
  prep_gcnT<<<dim3(24, 24, 2), dim3(32, 8), 0, stream>>>(gcn_w, QHB, gcnT1);

  // ---- object-level graph (512 graphs of n=50), chunked ----
  int nchunks = 512 / GC;
  for (int c = 0; c < nchunks; c++) {
    const u16* fc = Abf + (size_t)c * GC * 50 * 768;
    int mt = (R + 255) / 256;
    gemm_bt<<<dim3(mt, 9), 512, 0, stream>>>(fc, QHB, biasQH, QHc, R, 2304, 768);
    fused_l1<64><<<GC, 512, 0, stream>>>(QHc, ln_g, ln_b, adjGc, X1c, 50);
    gemm_bt<<<dim3(mt, 3), 512, 0, stream>>>(X1c, gcnT1, nullptr, H2c, R, 768, 768);
    fused_l2<64><<<GC, 512, 0, stream>>>(adjGc, H2c, ln_g + 768, ln_b + 768,
                                         Xf + (size_t)c * GC * 768, 50, 1.f / 50.f);
  }

  // ---- frame-level graph (16 graphs of n=32) ----
  gemm_bt<<<dim3(2, 9), 512, 0, stream>>>(Xf, QHB, biasQH, QHf, 512, 2304, 768);
  fused_l1<32><<<16, 512, 0, stream>>>(QHf, ln_g, ln_b, adjFb, X1f, 32);
  gemm_bt<<<dim3(2, 3), 512, 0, stream>>>(X1f, gcnT1, nullptr, H2f, 512, 768, 768);
  fused_l2<32><<<16, 512, 0, stream>>>(adjFb, H2f, ln_g + 768, ln_b + 768, Xm, 32, 1.f / 32.f);

  // ---- head ----
  concat_y<<<16, 384, 0, stream>>>(Xm, fgs, yout);
  fc1_relu<<<192, 256, 0, stream>>>(yout, fc1_w, fc1_b, hbuf);
  fc2_out<<<100, 256, 0, stream>>>(hbuf, fc2_w, fc2_b, out);
}

// Round 6
// 553.031 us; speedup vs baseline: 1.2110x; 1.2110x over previous
//
#include <hip/hip_runtime.h>
#include <hip/hip_bf16.h>

typedef unsigned short u16;
typedef unsigned int   u32;
typedef __attribute__((ext_vector_type(8))) short short8;
typedef __attribute__((ext_vector_type(4))) float float4v;

// ---------- helpers ----------
__device__ __forceinline__ float bf2f(u16 u){ union{u32 i; float f;} c; c.i = ((u32)u) << 16; return c.f; }
__device__ __forceinline__ float bflo(u32 u){ union{u32 i; float f;} c; c.i = u << 16; return c.f; }
__device__ __forceinline__ float bfhi(u32 u){ union{u32 i; float f;} c; c.i = u & 0xFFFF0000u; return c.f; }
__device__ __forceinline__ u16 f2bf(float f){
  union{float f; u32 i;} c; c.f = f; u32 x = c.i;
  return (u16)((x + 0x7FFFu + ((x >> 16) & 1u)) >> 16);   // RNE
}
// packed f32x2 -> bf16x2, RNE (v_cvt_pk_bf16_f32)
__device__ __forceinline__ u32 pack2(float a, float b){
  union { __hip_bfloat162 h; u32 u; } c;
  c.h = __float22bfloat162_rn(float2{a, b});
  return c.u;
}

__device__ __forceinline__ void async16(const void* g, void* l){
  __builtin_amdgcn_global_load_lds((const __attribute__((address_space(1))) void*)g,
                                   (__attribute__((address_space(3))) void*)l, 16, 0, 0);
}

// ---------- prep: feats fp32 -> bf16 (done ONCE) ----------
__global__ void __launch_bounds__(256) conv_bf16(const float* __restrict__ src, u16* __restrict__ dst, int n8)
{
  int t = blockIdx.x * 256 + threadIdx.x;
  int stride = gridDim.x * 256;
  for (int i = t; i < n8; i += stride) {
    float4 a = ((const float4*)src)[2 * i];
    float4 b = ((const float4*)src)[2 * i + 1];
    uint4 o = { pack2(a.x, a.y), pack2(a.z, a.w), pack2(b.x, b.y), pack2(b.z, b.w) };
    ((uint4*)dst)[i] = o;
  }
}

// ---------- generic 768x768 fp32 -> bf16 transpose: dst[c][r] = src[r][c] ----------
__global__ void transpose_bf16(const float* __restrict__ src, u16* __restrict__ dst)
{
  __shared__ float tile[32][33];
  int r0 = blockIdx.y * 32, c0 = blockIdx.x * 32;
  int tx = threadIdx.x, ty = threadIdx.y;           // 32 x 8
  for (int i = 0; i < 32; i += 8) tile[ty + i][tx] = src[(size_t)(r0 + ty + i) * 768 + c0 + tx];
  __syncthreads();
  for (int i = 0; i < 32; i += 8) dst[(size_t)(c0 + ty + i) * 768 + r0 + tx] = f2bf(tile[tx][ty + i]);
}

// gcn_w[l][d][o] -> l==0: QHB rows 768+o ; l==1: gcnT1[o][d]   (fp32 -> bf16, transposed)
__global__ void prep_gcnT(const float* __restrict__ gcn, u16* __restrict__ QHB, u16* __restrict__ gcnT1)
{
  __shared__ float tile[32][33];
  int l = blockIdx.z;
  int d0 = blockIdx.y * 32, o0 = blockIdx.x * 32;
  int tx = threadIdx.x, ty = threadIdx.y;           // 32 x 8
  const float* src = gcn + (size_t)l * 589824;
  u16* dst = (l == 0) ? (QHB + (size_t)768 * 768) : gcnT1;
  for (int i = 0; i < 32; i += 8) tile[ty + i][tx] = src[(size_t)(d0 + ty + i) * 768 + o0 + tx];
  __syncthreads();
  for (int i = 0; i < 32; i += 8) dst[(size_t)(o0 + ty + i) * 768 + d0 + tx] = f2bf(tile[tx][ty + i]);
}

// ---------- prep: u = Wq^T bk, v = Wk^T bq (uv[0:768]=u, uv[768:1536]=v), cbuf[0] = bq.bk ----------
__global__ void __launch_bounds__(256) prep_uv(const float* __restrict__ wq, const float* __restrict__ wk,
                                               const float* __restrict__ wqb, const float* __restrict__ wkb,
                                               float* __restrict__ uv, float* __restrict__ cbuf)
{
  if (blockIdx.x < 6) {
    int t = blockIdx.x * 256 + threadIdx.x;
    if (t < 768) {
      float a = 0.f;
      for (int o = 0; o < 768; o++) a += wq[(size_t)o * 768 + t] * wkb[o];
      uv[t] = a;
    } else {
      int d = t - 768;
      float a = 0.f;
      for (int o = 0; o < 768; o++) a += wk[(size_t)o * 768 + d] * wqb[o];
      uv[t] = a;
    }
  } else {
    __shared__ float red[256];
    float a = 0.f;
    for (int o = threadIdx.x; o < 768; o += 256) a += wqb[o] * wkb[o];
    red[threadIdx.x] = a; __syncthreads();
    if (threadIdx.x == 0) { float s = 0.f; for (int i = 0; i < 256; i++) s += red[i]; cbuf[0] = s; }
  }
}

// ---------- per-row rank-1 bias terms: p[i] = x_i.u + c ; q[i] = x_i.v ----------
__global__ void __launch_bounds__(256) row_pq(const u16* __restrict__ X, const float* __restrict__ uv,
                                              const float* __restrict__ cbuf, float* __restrict__ p,
                                              float* __restrict__ q, int Mrows)
{
  __shared__ float us[768], vs[768];
  int tid = threadIdx.x, lane = tid & 63, w = tid >> 6;
  for (int i = tid; i < 768; i += 256) { us[i] = uv[i]; vs[i] = uv[768 + i]; }
  __syncthreads();
  int row = blockIdx.x * 4 + w;
  if (row >= Mrows) return;
  const u16* xr = X + (size_t)row * 768;
  float ap = 0.f, aq = 0.f;
  for (int k = 0; k < 12; k++) {
    int d = k * 64 + lane;
    float x = bf2f(xr[d]);
    ap += x * us[d]; aq += x * vs[d];
  }
  for (int m = 1; m <= 32; m <<= 1) { ap += __shfl_xor(ap, m); aq += __shfl_xor(aq, m); }
  if (lane == 0) { p[row] = ap + cbuf[0]; q[row] = aq; }
}

// ---------- main GEMM: C[m][n] = sum_k A[m][k]*B[n][k] + bias[n] ----------
// 128x128 tile, BK=64 (32 MFMA per barrier-pair), round-3 verified structure.
// global_load_lds w/ pre-swizzled SOURCE chunk (l&7)^(l>>3), linear LDS, read at
// slot (ks*4+quad)^(l15&7): conflict-free. M,N multiples of 128 required.
__global__ void __launch_bounds__(256) gemm_bt(const u16* __restrict__ A, const u16* __restrict__ Bw,
                                               const float* __restrict__ bias, u16* __restrict__ C,
                                               int M, int N, int K)
{
  __shared__ __attribute__((aligned(16))) u16 As[128 * 64];
  __shared__ __attribute__((aligned(16))) u16 Bs[128 * 64];
  int tid = threadIdx.x, lane = tid & 63, wid = tid >> 6;
  int wm = wid >> 1, wn = wid & 1;
  size_t m0 = (size_t)blockIdx.x * 128, n0 = (size_t)blockIdx.y * 128;

  float4v acc[4][4];
  for (int r = 0; r < 4; r++) for (int c = 0; c < 4; c++) acc[r][c] = (float4v){0.f, 0.f, 0.f, 0.f};

  int srow8  = lane >> 3;
  int schunk = (lane & 7) ^ srow8;
  const u16* gA[4]; const u16* gB[4];
  u16* lA[4]; u16* lB[4];
#pragma unroll
  for (int j = 0; j < 4; j++) {
    int r = 32 * wid + 8 * j + srow8;
    gA[j] = A  + (m0 + r) * (size_t)K + schunk * 8;
    gB[j] = Bw + (n0 + r) * (size_t)K + schunk * 8;
    lA[j] = &As[(32 * wid + 8 * j) * 64];
    lB[j] = &Bs[(32 * wid + 8 * j) * 64];
  }

  int l15 = lane & 15, quad = lane >> 4;
  int s0 = quad ^ (l15 & 7);

  for (int kt = 0; kt < K; kt += 64) {
#pragma unroll
    for (int j = 0; j < 4; j++) {
      async16(gA[j] + kt, lA[j]);
      async16(gB[j] + kt, lB[j]);
    }
    __syncthreads();
#pragma unroll
    for (int ks = 0; ks < 2; ks++) {
      int so = (s0 ^ (ks << 2)) * 8;
      short8 af[4], bfr[4];
#pragma unroll
      for (int r = 0; r < 4; r++) af[r]  = *(const short8*)&As[(wm * 64 + r * 16 + l15) * 64 + so];
#pragma unroll
      for (int c = 0; c < 4; c++) bfr[c] = *(const short8*)&Bs[(wn * 64 + c * 16 + l15) * 64 + so];
#pragma unroll
      for (int r = 0; r < 4; r++)
#pragma unroll
        for (int c = 0; c < 4; c++)
          acc[r][c] = __builtin_amdgcn_mfma_f32_16x16x32_bf16(af[r], bfr[c], acc[r][c], 0, 0, 0);
    }
    __syncthreads();
  }

  int quad4 = quad * 4;
  for (int c = 0; c < 4; c++) {
    int n = (int)n0 + wn * 64 + c * 16 + l15;
    float bv = bias ? bias[n] : 0.f;
    for (int r = 0; r < 4; r++) {
      size_t mbase = m0 + wm * 64 + r * 16 + quad4;
      for (int t = 0; t < 4; t++)
        C[(mbase + t) * (size_t)N + n] = f2bf(acc[r][c][t] + bv);
    }
  }
}

// ================= fused per-graph adjacency kernels =================
// TH rows (stride 1536): [0,768)=T = x.Wqk, [768,1536)=H1. AR = raw x rows (stride 768).
// S_ij = T_i . x_j + p_i + q_j  (p,q,c precomputed rank-1 bias terms; zero when biases zero).
// L1: S per-wave direct-from-global MFMA -> +bias -> rowsum(S^2) -> adj -> X1=relu(LN(adj@H1)).
// L2: load adj -> relu(LN(adj@H2)) -> column mean only.
// Stage 2: HT double-buffered (one barrier/chunk) + depth-1 register prefetch.

template<int NP>
__global__ void __launch_bounds__(512) fused_l1(const u16* __restrict__ TH, const u16* __restrict__ AR,
                                                const float* __restrict__ pb, const float* __restrict__ qb,
                                                const float* __restrict__ lng, const float* __restrict__ lnb,
                                                u16* __restrict__ adjG, u16* __restrict__ X, int n)
{
  constexpr int ST = 72;
  constexpr int TPW = (NP == 64) ? 2 : 1;
  __shared__ __attribute__((aligned(16))) u16 adjb[NP * ST];
  __shared__ __attribute__((aligned(16))) u16 HT[2][64 * ST];
  __shared__ float rsum[NP];
  __shared__ float stats[NP][2];
  __shared__ float bc[NP][2];
  __shared__ float ps[NP], qs[NP];
  __shared__ float lg[768], lb[768];

  int g = blockIdx.x;
  int tid = threadIdx.x, lane = tid & 63, w = tid >> 6;
  int l15 = lane & 15, quad = lane >> 4;

  for (int i = tid; i < 768; i += 512) { lg[i] = lng[i]; lb[i] = lnb[i]; }
  if (tid < NP) {
    rsum[tid] = 0.f; stats[tid][0] = 0.f; stats[tid][1] = 0.f;
    ps[tid] = (tid < n) ? pb[(size_t)g * n + tid] : 0.f;
    qs[tid] = (tid < n) ? qb[(size_t)g * n + tid] : 0.f;
  }
  __syncthreads();

  // ---- stage 1: S = T @ x^T, per-wave, no LDS/barriers ----
  int mt, nt0; bool s_act;
  if (NP == 64) { mt = w & 3; nt0 = (w >> 2) * 2; s_act = true; }
  else          { mt = w & 1; nt0 = w >> 1;       s_act = (w < 4); }

  int rowA = mt * 16 + l15;
  bool aok = rowA < n;
  const u16* tA  = TH + ((size_t)g * n + rowA) * 1536 + quad * 8;
  int rowB0 = (nt0) * 16 + l15, rowB1 = (nt0 + TPW - 1) * 16 + l15;
  bool b0ok = rowB0 < n, b1ok = rowB1 < n;
  const u16* pB0 = AR + ((size_t)g * n + rowB0) * 768 + quad * 8;
  const u16* pB1 = AR + ((size_t)g * n + rowB1) * 768 + quad * 8;

  float4v sacc[TPW];
  for (int j = 0; j < TPW; j++) sacc[j] = (float4v){0.f, 0.f, 0.f, 0.f};

  if (s_act) {
    for (int kt = 0; kt < 768; kt += 32) {
      uint4 av = {0,0,0,0}, bv0 = {0,0,0,0}, bv1 = {0,0,0,0};
      if (aok)  av  = *(const uint4*)(tA + kt);
      if (b0ok) bv0 = *(const uint4*)(pB0 + kt);
      if (TPW == 2 && b1ok) bv1 = *(const uint4*)(pB1 + kt);
      short8 a = *(short8*)&av;
      sacc[0] = __builtin_amdgcn_mfma_f32_16x16x32_bf16(a, *(short8*)&bv0, sacc[0], 0, 0, 0);
      if (TPW == 2)
        sacc[1] = __builtin_amdgcn_mfma_f32_16x16x32_bf16(a, *(short8*)&bv1, sacc[1], 0, 0, 0);
    }
    // add rank-1 bias terms; mask cols >= n so they don't pollute rowsum
    for (int j = 0; j < TPW; j++) {
      int col = (nt0 + j) * 16 + l15;
      bool cok = col < n;
      for (int t = 0; t < 4; t++) {
        int row = mt * 16 + quad * 4 + t;
        sacc[j][t] = cok ? (sacc[j][t] + ps[row] + qs[col]) : 0.f;
      }
    }
    // partial row sums of S^2 (reduce over the 16 cols held across l15 lanes)
    for (int t = 0; t < 4; t++) {
      float s = 0.f;
      for (int j = 0; j < TPW; j++) { float v = sacc[j][t]; s += v * v; }
      s += __shfl_xor(s, 1); s += __shfl_xor(s, 2); s += __shfl_xor(s, 4); s += __shfl_xor(s, 8);
      if (l15 == 0) atomicAdd(&rsum[mt * 16 + quad * 4 + t], s);
    }
  }
  __syncthreads();
  if (tid < NP) rsum[tid] = 1.0f / fmaxf(rsum[tid], 1e-12f);
  __syncthreads();
  if (s_act) {
    u16* gadj = adjG + (size_t)g * NP * NP;
    for (int j = 0; j < TPW; j++)
      for (int t = 0; t < 4; t++) {
        int row = mt * 16 + quad * 4 + t, col = (nt0 + j) * 16 + l15;
        float v = sacc[j][t];
        u16 b = f2bf(v * v * rsum[row]);
        adjb[row * ST + col] = b;
        gadj[row * NP + col] = b;
      }
  }
  __syncthreads();

  // ---- stage 2: X = adj @ H1, 12 chunks of 64 d-cols ----
  int m2, nt20;
  if (NP == 64) { m2 = w & 3; nt20 = (w >> 2) * 2; }
  else          { m2 = w & 1; nt20 = w >> 1; }

  float4v xacc[12][TPW];
#pragma unroll
  for (int ch = 0; ch < 12; ch++) for (int j = 0; j < TPW; j++) xacc[ch][j] = (float4v){0.f,0.f,0.f,0.f};

  int hj  = tid & (NP - 1);
  int hseg= (NP == 64) ? w : ((tid >> 5) & 7);
  bool hact = (NP == 64) ? true : (tid < NP * 8);
  const u16* hbase = TH + ((size_t)g * n + hj) * 1536 + 768 + hseg * 8;

  uint4 hcur = {0,0,0,0};
  if (hact && hj < n) hcur = *(const uint4*)(hbase);

#pragma unroll
  for (int ch = 0; ch < 12; ch++) {
    uint4 hnext = {0,0,0,0};
    if (ch < 11 && hact && hj < n) hnext = *(const uint4*)(hbase + (ch + 1) * 64);
    u16* htb = HT[ch & 1];
    if (hact) {
      const u16* ep = (const u16*)&hcur;
      for (int i = 0; i < 8; i++) htb[(hseg * 8 + i) * ST + hj] = ep[i];
    }
    __syncthreads();
    for (int k = 0; k < NP / 32; k++) {
      short8 a = *(const short8*)&adjb[(m2 * 16 + l15) * ST + k * 32 + quad * 8];
      for (int j = 0; j < TPW; j++) {
        short8 b = *(const short8*)&htb[((nt20 + j) * 16 + l15) * ST + k * 32 + quad * 8];
        xacc[ch][j] = __builtin_amdgcn_mfma_f32_16x16x32_bf16(a, b, xacc[ch][j], 0, 0, 0);
      }
    }
    hcur = hnext;
  }

  // ---- LN stats ----
  float ssum[4] = {0,0,0,0}, ssq[4] = {0,0,0,0};
#pragma unroll
  for (int ch = 0; ch < 12; ch++)
    for (int j = 0; j < TPW; j++)
      for (int t = 0; t < 4; t++) { float v = xacc[ch][j][t]; ssum[t] += v; ssq[t] += v * v; }
  for (int m = 1; m <= 8; m <<= 1)
    for (int t = 0; t < 4; t++) { ssum[t] += __shfl_xor(ssum[t], m); ssq[t] += __shfl_xor(ssq[t], m); }
  if (l15 == 0)
    for (int t = 0; t < 4; t++) {
      atomicAdd(&stats[m2 * 16 + quad * 4 + t][0], ssum[t]);
      atomicAdd(&stats[m2 * 16 + quad * 4 + t][1], ssq[t]);
    }
  __syncthreads();
  if (tid < NP) {
    float mu = stats[tid][0] * (1.f / 768.f);
    float var = stats[tid][1] * (1.f / 768.f) - mu * mu;
    bc[tid][0] = mu; bc[tid][1] = rsqrtf(fmaxf(var, 0.f) + 1e-5f);
  }
  __syncthreads();

  // ---- LN + relu + write X ----
#pragma unroll
  for (int ch = 0; ch < 12; ch++)
    for (int j = 0; j < TPW; j++)
      for (int t = 0; t < 4; t++) {
        int row = m2 * 16 + quad * 4 + t;
        if (row < n) {
          int d = ch * 64 + (nt20 + j) * 16 + l15;
          float v = fmaxf((xacc[ch][j][t] - bc[row][0]) * bc[row][1] * lg[d] + lb[d], 0.f);
          X[((size_t)g * n + row) * 768 + d] = f2bf(v);
        }
      }
}

template<int NP>
__global__ void __launch_bounds__(512) fused_l2(const u16* __restrict__ adjG, const u16* __restrict__ H,
                                                const float* __restrict__ lng, const float* __restrict__ lnb,
                                                u16* __restrict__ Xmean, int n, float inv)
{
  constexpr int ST = 72;
  constexpr int TPW = (NP == 64) ? 2 : 1;
  __shared__ __attribute__((aligned(16))) u16 adjb[NP * ST];
  __shared__ __attribute__((aligned(16))) u16 HT[2][64 * ST];
  __shared__ float stats[NP][2];
  __shared__ float bc[NP][2];
  __shared__ float colsum[768];
  __shared__ float lg[768], lb[768];

  int g = blockIdx.x;
  int tid = threadIdx.x, lane = tid & 63, w = tid >> 6;
  int l15 = lane & 15, quad = lane >> 4;

  for (int i = tid; i < 768; i += 512) { lg[i] = lng[i]; lb[i] = lnb[i]; colsum[i] = 0.f; }
  if (tid < NP) { stats[tid][0] = 0.f; stats[tid][1] = 0.f; }
  if (tid * 8 < NP * NP) {
    int row = (tid * 8) / NP, c0 = (tid * 8) % NP;
    uint4 v = *(const uint4*)(adjG + (size_t)g * NP * NP + row * NP + c0);
    *(uint4*)&adjb[row * ST + c0] = v;
  }

  int m2, nt20;
  if (NP == 64) { m2 = w & 3; nt20 = (w >> 2) * 2; }
  else          { m2 = w & 1; nt20 = w >> 1; }

  float4v xacc[12][TPW];
#pragma unroll
  for (int ch = 0; ch < 12; ch++) for (int j = 0; j < TPW; j++) xacc[ch][j] = (float4v){0.f,0.f,0.f,0.f};

  int hj  = tid & (NP - 1);
  int hseg= (NP == 64) ? w : ((tid >> 5) & 7);
  bool hact = (NP == 64) ? true : (tid < NP * 8);
  const u16* hbase = H + ((size_t)g * n + hj) * 768 + hseg * 8;

  uint4 hcur = {0,0,0,0};
  if (hact && hj < n) hcur = *(const uint4*)(hbase);

  __syncthreads();   // adjb + colsum/stats init visible

#pragma unroll
  for (int ch = 0; ch < 12; ch++) {
    uint4 hnext = {0,0,0,0};
    if (ch < 11 && hact && hj < n) hnext = *(const uint4*)(hbase + (ch + 1) * 64);
    u16* htb = HT[ch & 1];
    if (hact) {
      const u16* ep = (const u16*)&hcur;
      for (int i = 0; i < 8; i++) htb[(hseg * 8 + i) * ST + hj] = ep[i];
    }
    __syncthreads();
    for (int k = 0; k < NP / 32; k++) {
      short8 a = *(const short8*)&adjb[(m2 * 16 + l15) * ST + k * 32 + quad * 8];
      for (int j = 0; j < TPW; j++) {
        short8 b = *(const short8*)&htb[((nt20 + j) * 16 + l15) * ST + k * 32 + quad * 8];
        xacc[ch][j] = __builtin_amdgcn_mfma_f32_16x16x32_bf16(a, b, xacc[ch][j], 0, 0, 0);
      }
    }
    hcur = hnext;
  }

  float ssum[4] = {0,0,0,0}, ssq[4] = {0,0,0,0};
#pragma unroll
  for (int ch = 0; ch < 12; ch++)
    for (int j = 0; j < TPW; j++)
      for (int t = 0; t < 4; t++) { float v = xacc[ch][j][t]; ssum[t] += v; ssq[t] += v * v; }
  for (int m = 1; m <= 8; m <<= 1)
    for (int t = 0; t < 4; t++) { ssum[t] += __shfl_xor(ssum[t], m); ssq[t] += __shfl_xor(ssq[t], m); }
  if (l15 == 0)
    for (int t = 0; t < 4; t++) {
      atomicAdd(&stats[m2 * 16 + quad * 4 + t][0], ssum[t]);
      atomicAdd(&stats[m2 * 16 + quad * 4 + t][1], ssq[t]);
    }
  __syncthreads();
  if (tid < NP) {
    float mu = stats[tid][0] * (1.f / 768.f);
    float var = stats[tid][1] * (1.f / 768.f) - mu * mu;
    bc[tid][0] = mu; bc[tid][1] = rsqrtf(fmaxf(var, 0.f) + 1e-5f);
  }
  __syncthreads();

#pragma unroll
  for (int ch = 0; ch < 12; ch++)
    for (int j = 0; j < TPW; j++)
      for (int t = 0; t < 4; t++) {
        int row = m2 * 16 + quad * 4 + t;
        int d = ch * 64 + (nt20 + j) * 16 + l15;
        float v = fmaxf((xacc[ch][j][t] - bc[row][0]) * bc[row][1] * lg[d] + lb[d], 0.f);
        float vm = (row < n) ? v : 0.f;
        vm += __shfl_xor(vm, 16);
        vm += __shfl_xor(vm, 32);
        if (quad == 0) atomicAdd(&colsum[d], vm);
      }
  __syncthreads();
  if (tid < 384)
    ((u32*)Xmean)[(size_t)g * 384 + tid] = pack2(colsum[tid * 2] * inv, colsum[tid * 2 + 1] * inv);
}

// ---------- concat: y = [bf2f(Xm) ; fgs] fp32 (in d_out) ----------
__global__ void __launch_bounds__(384) concat_y(const u16* __restrict__ Xm,
                                                const float* __restrict__ fgs, float* __restrict__ yout)
{
  int b = blockIdx.x, tid = threadIdx.x;
  u32 u = ((const u32*)Xm)[(size_t)b * 384 + tid];
  int d0 = tid * 2;
  yout[(size_t)b * 1536 + d0]     = bflo(u);
  yout[(size_t)b * 1536 + d0 + 1] = bfhi(u);
  yout[(size_t)b * 1536 + 768 + d0]     = fgs[(size_t)b * 768 + d0];
  yout[(size_t)b * 1536 + 768 + d0 + 1] = fgs[(size_t)b * 768 + d0 + 1];
}

// ---------- classifier ----------
__global__ void __launch_bounds__(256) fc1_relu(const float* __restrict__ yout,
                                                const float* __restrict__ fc1w, const float* __restrict__ fc1b,
                                                float* __restrict__ h)
{
  int o = blockIdx.x * 4 + (threadIdx.x >> 6);
  int lane = threadIdx.x & 63;
  float acc[16];
  for (int b = 0; b < 16; b++) acc[b] = 0.f;
  const float4* wr = (const float4*)(fc1w + (size_t)o * 1536);
  for (int k4 = lane; k4 < 384; k4 += 64) {
    float4 wv = wr[k4];
    for (int b = 0; b < 16; b++) {
      float4 yv = ((const float4*)(yout + (size_t)b * 1536))[k4];
      acc[b] += wv.x * yv.x + wv.y * yv.y + wv.z * yv.z + wv.w * yv.w;
    }
  }
  for (int m = 1; m <= 32; m <<= 1)
    for (int b = 0; b < 16; b++) acc[b] += __shfl_xor(acc[b], m);
  if (lane < 16) h[(size_t)lane * 768 + o] = fmaxf(acc[lane] + fc1b[o], 0.f);
}

__global__ void __launch_bounds__(256) fc2_out(const float* __restrict__ h,
                                               const float* __restrict__ fc2w, const float* __restrict__ fc2b,
                                               float* __restrict__ logits)
{
  int o = blockIdx.x * 4 + (threadIdx.x >> 6);
  int lane = threadIdx.x & 63;
  float acc[16];
  for (int b = 0; b < 16; b++) acc[b] = 0.f;
  const float4* wr = (const float4*)(fc2w + (size_t)o * 768);
  for (int k4 = lane; k4 < 192; k4 += 64) {
    float4 wv = wr[k4];
    for (int b = 0; b < 16; b++) {
      float4 hv = ((const float4*)(h + (size_t)b * 768))[k4];
      acc[b] += wv.x * hv.x + wv.y * hv.y + wv.z * hv.z + wv.w * hv.w;
    }
  }
  for (int m = 1; m <= 32; m <<= 1)
    for (int b = 0; b < 16; b++) acc[b] += __shfl_xor(acc[b], m);
  if (lane < 16) logits[(size_t)lane * 400 + o] = acc[lane] + fc2b[o];
}

// ---------- launch ----------
extern "C" void kernel_launch(void* const* d_in, const int* in_sizes, int n_in,
                              void* d_out, int out_size, void* d_ws, size_t ws_size,
                              hipStream_t stream) {
  const float* feats = (const float*)d_in[0];
  const float* fgs   = (const float*)d_in[1];
  const float* wq_w  = (const float*)d_in[3];
  const float* wq_b  = (const float*)d_in[4];
  const float* wk_w  = (const float*)d_in[5];
  const float* wk_b  = (const float*)d_in[6];
  const float* gcn_w = (const float*)d_in[7];
  const float* ln_g  = (const float*)d_in[8];
  const float* ln_b  = (const float*)d_in[9];
  const float* fc1_w = (const float*)d_in[10];
  const float* fc1_b = (const float*)d_in[11];
  const float* fc2_w = (const float*)d_in[12];
  const float* fc2_b = (const float*)d_in[13];
  float* out  = (float*)d_out;
  float* yout = out + 16 * 400;               // y region: [16][1536] fp32

  char* ws = (char*)d_ws;
  size_t off = 0;
  auto alloc = [&](size_t b){ size_t r = off; off = (off + b + 255) & ~(size_t)255; return r; };
  // persistent
  u16*  QHB    = (u16*) (ws + alloc((size_t)1536 * 768 * 2));    // [Wqk^T; gcn0^T] bf16
  u16*  gcnT1  = (u16*) (ws + alloc((size_t)768 * 768 * 2));
  u16*  WqT    = (u16*) (ws + alloc((size_t)768 * 768 * 2));
  u16*  WkT    = (u16*) (ws + alloc((size_t)768 * 768 * 2));
  float* uv    = (float*)(ws + alloc((size_t)1536 * 4));
  float* cbuf  = (float*)(ws + alloc((size_t)4));
  u16*  Abf    = (u16*) (ws + alloc((size_t)25600 * 768 * 2));   // feats pre-converted to bf16
  float* pObj  = (float*)(ws + alloc((size_t)25600 * 4));
  float* qObj  = (float*)(ws + alloc((size_t)25600 * 4));
  float* pF    = (float*)(ws + alloc((size_t)512 * 4));
  float* qF    = (float*)(ws + alloc((size_t)512 * 4));
  u16*  Xf     = (u16*) (ws + alloc((size_t)512 * 768 * 2));
  u16*  QHf    = (u16*) (ws + alloc((size_t)512 * 1536 * 2));
  u16*  X1f    = (u16*) (ws + alloc((size_t)512 * 768 * 2));
  u16*  H2f    = (u16*) (ws + alloc((size_t)512 * 768 * 2));
  u16*  adjFb  = (u16*) (ws + alloc((size_t)16 * 32 * 32 * 2));
  u16*  Xm     = (u16*) (ws + alloc((size_t)16 * 768 * 2));
  float* hbuf  = (float*)(ws + alloc((size_t)16 * 768 * 4));
  size_t base = off;

  // per-chunk: QHc [R][1536] + X1c [R][768] + adjGc [GC][64][64] bf16 (H2c aliases QHc)
  auto need = [&](int GC){
    size_t R = (size_t)GC * 50;
    return base + R * 1536 * 2 + 512 + R * 768 * 2 + 512 + (size_t)GC * 64 * 64 * 2 + 512;
  };
  int GC = 64;
  if (need(512) <= ws_size) GC = 512;
  else if (need(256) <= ws_size) GC = 256;
  else if (need(128) <= ws_size) GC = 128;
  int R = GC * 50;
  size_t off2 = base;
  auto alloc2 = [&](size_t b){ size_t r = off2; off2 = (off2 + b + 255) & ~(size_t)255; return r; };
  u16* QHc   = (u16*)(ws + alloc2((size_t)R * 1536 * 2));
  u16* X1c   = (u16*)(ws + alloc2((size_t)R * 768 * 2));
  u16* adjGc = (u16*)(ws + alloc2((size_t)GC * 64 * 64 * 2));
  u16* H2c   = QHc;                      // QHc dead after fused_l1

  // ---- prep ----
  transpose_bf16<<<dim3(24, 24), dim3(32, 8), 0, stream>>>(wq_w, WqT);   // WqT[d][o] = wq[o][d]
  transpose_bf16<<<dim3(24, 24), dim3(32, 8), 0, stream>>>(wk_w, WkT);
  prep_uv<<<7, 256, 0, stream>>>(wq_w, wk_w, wq_b, wk_b, uv, cbuf);
  // QHB rows 0-767: C[d'][d] = sum_o WkT[d'][o]*WqT[d][o] = Wqk[d][d']  (gemm1's B layout)
  gemm_bt<<<dim3(6, 6), 256, 0, stream>>>(WkT, WqT, nullptr, QHB, 768, 768, 768);
  prep_gcnT<<<dim3(24, 24, 2), dim3(32, 8), 0, stream>>>(gcn_w, QHB, gcnT1);
  conv_bf16<<<2048, 256, 0, stream>>>(feats, Abf, 25600 * 768 / 8);
  row_pq<<<6400, 256, 0, stream>>>(Abf, uv, cbuf, pObj, qObj, 25600);

  // ---- object-level graph (512 graphs of n=50), chunked ----
  int nchunks = 512 / GC;
  for (int c = 0; c < nchunks; c++) {
    const u16* fc = Abf + (size_t)c * GC * 50 * 768;
    gemm_bt<<<dim3(R / 128, 12), 256, 0, stream>>>(fc, QHB, nullptr, QHc, R, 1536, 768);
    fused_l1<64><<<GC, 512, 0, stream>>>(QHc, fc, pObj + (size_t)c * GC * 50, qObj + (size_t)c * GC * 50,
                                         ln_g, ln_b, adjGc, X1c, 50);
    gemm_bt<<<dim3(R / 128, 6), 256, 0, stream>>>(X1c, gcnT1, nullptr, H2c, R, 768, 768);
    fused_l2<64><<<GC, 512, 0, stream>>>(adjGc, H2c, ln_g + 768, ln_b + 768,
                                         Xf + (size_t)c * GC * 768, 50, 1.f / 50.f);
  }

  // ---- frame-level graph (16 graphs of n=32) ----
  row_pq<<<128, 256, 0, stream>>>(Xf, uv, cbuf, pF, qF, 512);
  gemm_bt<<<dim3(4, 12), 256, 0, stream>>>(Xf, QHB, nullptr, QHf, 512, 1536, 768);
  fused_l1<32><<<16, 512, 0, stream>>>(QHf, Xf, pF, qF, ln_g, ln_b, adjFb, X1f, 32);
  gemm_bt<<<dim3(4, 6), 256, 0, stream>>>(X1f, gcnT1, nullptr, H2f, 512, 768, 768);
  fused_l2<32><<<16, 512, 0, stream>>>(adjFb, H2f, ln_g + 768, ln_b + 768, Xm, 32, 1.f / 32.f);

  // ---- head ----
  concat_y<<<16, 384, 0, stream>>>(Xm, fgs, yout);
  fc1_relu<<<192, 256, 0, stream>>>(yout, fc1_w, fc1_b, hbuf);
  fc2_out<<<100, 256, 0, stream>>>(hbuf, fc2_w, fc2_b, out);
}

// Round 7
// 509.793 us; speedup vs baseline: 1.3137x; 1.0848x over previous
//
#include <hip/hip_runtime.h>
#include <hip/hip_bf16.h>

typedef unsigned short u16;
typedef unsigned int   u32;
typedef __attribute__((ext_vector_type(8))) short short8;
typedef __attribute__((ext_vector_type(4))) float float4v;

// ---------- helpers ----------
__device__ __forceinline__ float bf2f(u16 u){ union{u32 i; float f;} c; c.i = ((u32)u) << 16; return c.f; }
__device__ __forceinline__ float bflo(u32 u){ union{u32 i; float f;} c; c.i = u << 16; return c.f; }
__device__ __forceinline__ float bfhi(u32 u){ union{u32 i; float f;} c; c.i = u & 0xFFFF0000u; return c.f; }
__device__ __forceinline__ u16 f2bf(float f){
  union{float f; u32 i;} c; c.f = f; u32 x = c.i;
  return (u16)((x + 0x7FFFu + ((x >> 16) & 1u)) >> 16);   // RNE
}
// packed f32x2 -> bf16x2, RNE (v_cvt_pk_bf16_f32)
__device__ __forceinline__ u32 pack2(float a, float b){
  union { __hip_bfloat162 h; u32 u; } c;
  c.h = __float22bfloat162_rn(float2{a, b});
  return c.u;
}

__device__ __forceinline__ void async16(const void* g, void* l){
  __builtin_amdgcn_global_load_lds((const __attribute__((address_space(1))) void*)g,
                                   (__attribute__((address_space(3))) void*)l, 16, 0, 0);
}

// ---------- prep: all four 768x768 fp32 -> bf16 transposes in ONE launch ----------
// z=0: wq -> WqT ; z=1: wk -> WkT ; z=2: gcn[0] -> QHB rows 768.. ; z=3: gcn[1] -> gcnT1
__global__ void prep_w(const float* __restrict__ wq, const float* __restrict__ wk,
                       const float* __restrict__ gcn,
                       u16* __restrict__ WqT, u16* __restrict__ WkT,
                       u16* __restrict__ QHB768, u16* __restrict__ gcnT1)
{
  __shared__ float tile[32][33];
  int z = blockIdx.z;
  const float* src = (z == 0) ? wq : (z == 1) ? wk : gcn + (size_t)(z - 2) * 589824;
  u16* dst = (z == 0) ? WqT : (z == 1) ? WkT : (z == 2) ? QHB768 : gcnT1;
  int r0 = blockIdx.y * 32, c0 = blockIdx.x * 32;
  int tx = threadIdx.x, ty = threadIdx.y;           // 32 x 8
  for (int i = 0; i < 32; i += 8) tile[ty + i][tx] = src[(size_t)(r0 + ty + i) * 768 + c0 + tx];
  __syncthreads();
  for (int i = 0; i < 32; i += 8) dst[(size_t)(c0 + ty + i) * 768 + r0 + tx] = f2bf(tile[tx][ty + i]);
}

// ---------- prep: u = Wq^T bk (uv[0:768]), v = Wk^T bq (uv[768:1536]), cbuf[0] = bq.bk ----------
// blocks 0-11: u (64 outputs each, o split 4-way); 12-23: v; 24: c. No atomics.
__global__ void __launch_bounds__(256) prep_uv2(const float* __restrict__ wq, const float* __restrict__ wk,
                                                const float* __restrict__ wqb, const float* __restrict__ wkb,
                                                float* __restrict__ uv, float* __restrict__ cbuf)
{
  __shared__ float red[4][64];
  __shared__ float r2[256];
  int b = blockIdx.x, tid = threadIdx.x;
  if (b < 24) {
    const float* w  = (b < 12) ? wq : wk;
    const float* bs = (b < 12) ? wkb : wqb;
    int out = (b % 12) * 64 + (tid & 63);
    int oq = tid >> 6;
    float a = 0.f;
    for (int o = oq * 192; o < oq * 192 + 192; o++) a += w[(size_t)o * 768 + out] * bs[o];
    red[oq][tid & 63] = a;
    __syncthreads();
    if (tid < 64)
      uv[((b < 12) ? 0 : 768) + (b % 12) * 64 + tid] = red[0][tid] + red[1][tid] + red[2][tid] + red[3][tid];
  } else {
    float a = 0.f;
    for (int o = tid; o < 768; o += 256) a += wqb[o] * wkb[o];
    r2[tid] = a; __syncthreads();
    if (tid == 0) { float s = 0.f; for (int i = 0; i < 256; i++) s += r2[i]; cbuf[0] = s; }
  }
}

// ---------- feats fp32 -> bf16 + per-row p,q (fused: zero extra global traffic) ----------
// block handles 8 rows; thread = (row = tid>>5, 3 consecutive octets at (tid&31)*3).
// p[i] = x_i.u + c ; q[i] = x_i.v  computed from fp32 x while converting.
__global__ void __launch_bounds__(256) conv_pq(const float* __restrict__ src, u16* __restrict__ dst,
                                               const float* __restrict__ uv, const float* __restrict__ cbuf,
                                               float* __restrict__ p, float* __restrict__ q)
{
  __shared__ float us[768], vs[768];
  int tid = threadIdx.x, lane = tid & 63;
  for (int i = tid; i < 768; i += 256) { us[i] = uv[i]; vs[i] = uv[768 + i]; }
  __syncthreads();
  size_t rbase = (size_t)blockIdx.x * 8;
  int row = tid >> 5;                 // 0..7 (two rows per wave)
  int c3  = (tid & 31) * 3;           // starting octet within row
  const float* s = src + (rbase + row) * 768 + (size_t)c3 * 8;
  u16* d = dst + (rbase + row) * 768 + (size_t)c3 * 8;
  float ap = 0.f, aq = 0.f;
#pragma unroll
  for (int j = 0; j < 3; j++) {
    float4 a = ((const float4*)s)[j * 2];
    float4 b = ((const float4*)s)[j * 2 + 1];
    uint4 o = { pack2(a.x, a.y), pack2(a.z, a.w), pack2(b.x, b.y), pack2(b.z, b.w) };
    ((uint4*)d)[j] = o;
    const float* uu = &us[(c3 + j) * 8];
    const float* vv = &vs[(c3 + j) * 8];
    ap += a.x*uu[0] + a.y*uu[1] + a.z*uu[2] + a.w*uu[3] + b.x*uu[4] + b.y*uu[5] + b.z*uu[6] + b.w*uu[7];
    aq += a.x*vv[0] + a.y*vv[1] + a.z*vv[2] + a.w*vv[3] + b.x*vv[4] + b.y*vv[5] + b.z*vv[6] + b.w*vv[7];
  }
  for (int m = 1; m <= 16; m <<= 1) { ap += __shfl_xor(ap, m); aq += __shfl_xor(aq, m); }
  if ((lane & 31) == 0) {
    p[rbase + row] = ap + cbuf[0];
    q[rbase + row] = aq;
  }
}

// ---------- main GEMM: C[m][n] = sum_k A[m][k]*B[n][k] + bias[n] ----------
// 128x128 tile, BK=64 (32 MFMA per barrier-pair), round-3 verified structure.
// global_load_lds w/ pre-swizzled SOURCE chunk (l&7)^(l>>3), linear LDS, read at
// slot (ks*4+quad)^(l15&7): conflict-free. M,N multiples of 128 required.
__global__ void __launch_bounds__(256) gemm_bt(const u16* __restrict__ A, const u16* __restrict__ Bw,
                                               const float* __restrict__ bias, u16* __restrict__ C,
                                               int M, int N, int K)
{
  __shared__ __attribute__((aligned(16))) u16 As[128 * 64];
  __shared__ __attribute__((aligned(16))) u16 Bs[128 * 64];
  int tid = threadIdx.x, lane = tid & 63, wid = tid >> 6;
  int wm = wid >> 1, wn = wid & 1;
  size_t m0 = (size_t)blockIdx.x * 128, n0 = (size_t)blockIdx.y * 128;

  float4v acc[4][4];
  for (int r = 0; r < 4; r++) for (int c = 0; c < 4; c++) acc[r][c] = (float4v){0.f, 0.f, 0.f, 0.f};

  int srow8  = lane >> 3;
  int schunk = (lane & 7) ^ srow8;
  const u16* gA[4]; const u16* gB[4];
  u16* lA[4]; u16* lB[4];
#pragma unroll
  for (int j = 0; j < 4; j++) {
    int r = 32 * wid + 8 * j + srow8;
    gA[j] = A  + (m0 + r) * (size_t)K + schunk * 8;
    gB[j] = Bw + (n0 + r) * (size_t)K + schunk * 8;
    lA[j] = &As[(32 * wid + 8 * j) * 64];
    lB[j] = &Bs[(32 * wid + 8 * j) * 64];
  }

  int l15 = lane & 15, quad = lane >> 4;
  int s0 = quad ^ (l15 & 7);

  for (int kt = 0; kt < K; kt += 64) {
#pragma unroll
    for (int j = 0; j < 4; j++) {
      async16(gA[j] + kt, lA[j]);
      async16(gB[j] + kt, lB[j]);
    }
    __syncthreads();
#pragma unroll
    for (int ks = 0; ks < 2; ks++) {
      int so = (s0 ^ (ks << 2)) * 8;
      short8 af[4], bfr[4];
#pragma unroll
      for (int r = 0; r < 4; r++) af[r]  = *(const short8*)&As[(wm * 64 + r * 16 + l15) * 64 + so];
#pragma unroll
      for (int c = 0; c < 4; c++) bfr[c] = *(const short8*)&Bs[(wn * 64 + c * 16 + l15) * 64 + so];
#pragma unroll
      for (int r = 0; r < 4; r++)
#pragma unroll
        for (int c = 0; c < 4; c++)
          acc[r][c] = __builtin_amdgcn_mfma_f32_16x16x32_bf16(af[r], bfr[c], acc[r][c], 0, 0, 0);
    }
    __syncthreads();
  }

  int quad4 = quad * 4;
  for (int c = 0; c < 4; c++) {
    int n = (int)n0 + wn * 64 + c * 16 + l15;
    float bv = bias ? bias[n] : 0.f;
    for (int r = 0; r < 4; r++) {
      size_t mbase = m0 + wm * 64 + r * 16 + quad4;
      for (int t = 0; t < 4; t++)
        C[(mbase + t) * (size_t)N + n] = f2bf(acc[r][c][t] + bv);
    }
  }
}

// ================= fused per-graph adjacency kernels =================
// TH rows (stride 1536): [0,768)=T = x.Wqk, [768,1536)=H1. AR = raw x rows (stride 768).
// S_ij = T_i . x_j + p_i + q_j  (p,q,c precomputed rank-1 bias terms; zero when biases zero).
// L1: S per-wave direct-from-global MFMA -> +bias -> rowsum(S^2) -> adj -> X1=relu(LN(adj@H1)).
// L2: load adj -> relu(LN(adj@H2)) -> column mean; optional pOut/qOut epilogue computes
//     the NEXT level's rank-1 bias terms from the just-computed mean row (frees a kernel).
// Stage 2: HT double-buffered (one barrier/chunk) + depth-1 register prefetch.

template<int NP>
__global__ void __launch_bounds__(512) fused_l1(const u16* __restrict__ TH, const u16* __restrict__ AR,
                                                const float* __restrict__ pb, const float* __restrict__ qb,
                                                const float* __restrict__ lng, const float* __restrict__ lnb,
                                                u16* __restrict__ adjG, u16* __restrict__ X, int n)
{
  constexpr int ST = 72;
  constexpr int TPW = (NP == 64) ? 2 : 1;
  __shared__ __attribute__((aligned(16))) u16 adjb[NP * ST];
  __shared__ __attribute__((aligned(16))) u16 HT[2][64 * ST];
  __shared__ float rsum[NP];
  __shared__ float stats[NP][2];
  __shared__ float bc[NP][2];
  __shared__ float ps[NP], qs[NP];
  __shared__ float lg[768], lb[768];

  int g = blockIdx.x;
  int tid = threadIdx.x, lane = tid & 63, w = tid >> 6;
  int l15 = lane & 15, quad = lane >> 4;

  for (int i = tid; i < 768; i += 512) { lg[i] = lng[i]; lb[i] = lnb[i]; }
  if (tid < NP) {
    rsum[tid] = 0.f; stats[tid][0] = 0.f; stats[tid][1] = 0.f;
    ps[tid] = (tid < n) ? pb[(size_t)g * n + tid] : 0.f;
    qs[tid] = (tid < n) ? qb[(size_t)g * n + tid] : 0.f;
  }
  __syncthreads();

  // ---- stage 1: S = T @ x^T, per-wave, no LDS/barriers ----
  int mt, nt0; bool s_act;
  if (NP == 64) { mt = w & 3; nt0 = (w >> 2) * 2; s_act = true; }
  else          { mt = w & 1; nt0 = w >> 1;       s_act = (w < 4); }

  int rowA = mt * 16 + l15;
  bool aok = rowA < n;
  const u16* tA  = TH + ((size_t)g * n + rowA) * 1536 + quad * 8;
  int rowB0 = (nt0) * 16 + l15, rowB1 = (nt0 + TPW - 1) * 16 + l15;
  bool b0ok = rowB0 < n, b1ok = rowB1 < n;
  const u16* pB0 = AR + ((size_t)g * n + rowB0) * 768 + quad * 8;
  const u16* pB1 = AR + ((size_t)g * n + rowB1) * 768 + quad * 8;

  float4v sacc[TPW];
  for (int j = 0; j < TPW; j++) sacc[j] = (float4v){0.f, 0.f, 0.f, 0.f};

  if (s_act) {
    for (int kt = 0; kt < 768; kt += 32) {
      uint4 av = {0,0,0,0}, bv0 = {0,0,0,0}, bv1 = {0,0,0,0};
      if (aok)  av  = *(const uint4*)(tA + kt);
      if (b0ok) bv0 = *(const uint4*)(pB0 + kt);
      if (TPW == 2 && b1ok) bv1 = *(const uint4*)(pB1 + kt);
      short8 a = *(short8*)&av;
      sacc[0] = __builtin_amdgcn_mfma_f32_16x16x32_bf16(a, *(short8*)&bv0, sacc[0], 0, 0, 0);
      if (TPW == 2)
        sacc[1] = __builtin_amdgcn_mfma_f32_16x16x32_bf16(a, *(short8*)&bv1, sacc[1], 0, 0, 0);
    }
    // add rank-1 bias terms; mask cols >= n so they don't pollute rowsum
    for (int j = 0; j < TPW; j++) {
      int col = (nt0 + j) * 16 + l15;
      bool cok = col < n;
      for (int t = 0; t < 4; t++) {
        int row = mt * 16 + quad * 4 + t;
        sacc[j][t] = cok ? (sacc[j][t] + ps[row] + qs[col]) : 0.f;
      }
    }
    // partial row sums of S^2 (reduce over the 16 cols held across l15 lanes)
    for (int t = 0; t < 4; t++) {
      float s = 0.f;
      for (int j = 0; j < TPW; j++) { float v = sacc[j][t]; s += v * v; }
      s += __shfl_xor(s, 1); s += __shfl_xor(s, 2); s += __shfl_xor(s, 4); s += __shfl_xor(s, 8);
      if (l15 == 0) atomicAdd(&rsum[mt * 16 + quad * 4 + t], s);
    }
  }
  __syncthreads();
  if (tid < NP) rsum[tid] = 1.0f / fmaxf(rsum[tid], 1e-12f);
  __syncthreads();
  if (s_act) {
    u16* gadj = adjG + (size_t)g * NP * NP;
    for (int j = 0; j < TPW; j++)
      for (int t = 0; t < 4; t++) {
        int row = mt * 16 + quad * 4 + t, col = (nt0 + j) * 16 + l15;
        float v = sacc[j][t];
        u16 b = f2bf(v * v * rsum[row]);
        adjb[row * ST + col] = b;
        gadj[row * NP + col] = b;
      }
  }
  __syncthreads();

  // ---- stage 2: X = adj @ H1, 12 chunks of 64 d-cols ----
  int m2, nt20;
  if (NP == 64) { m2 = w & 3; nt20 = (w >> 2) * 2; }
  else          { m2 = w & 1; nt20 = w >> 1; }

  float4v xacc[12][TPW];
#pragma unroll
  for (int ch = 0; ch < 12; ch++) for (int j = 0; j < TPW; j++) xacc[ch][j] = (float4v){0.f,0.f,0.f,0.f};

  int hj  = tid & (NP - 1);
  int hseg= (NP == 64) ? w : ((tid >> 5) & 7);
  bool hact = (NP == 64) ? true : (tid < NP * 8);
  const u16* hbase = TH + ((size_t)g * n + hj) * 1536 + 768 + hseg * 8;

  uint4 hcur = {0,0,0,0};
  if (hact && hj < n) hcur = *(const uint4*)(hbase);

#pragma unroll
  for (int ch = 0; ch < 12; ch++) {
    uint4 hnext = {0,0,0,0};
    if (ch < 11 && hact && hj < n) hnext = *(const uint4*)(hbase + (ch + 1) * 64);
    u16* htb = HT[ch & 1];
    if (hact) {
      const u16* ep = (const u16*)&hcur;
      for (int i = 0; i < 8; i++) htb[(hseg * 8 + i) * ST + hj] = ep[i];
    }
    __syncthreads();
    for (int k = 0; k < NP / 32; k++) {
      short8 a = *(const short8*)&adjb[(m2 * 16 + l15) * ST + k * 32 + quad * 8];
      for (int j = 0; j < TPW; j++) {
        short8 b = *(const short8*)&htb[((nt20 + j) * 16 + l15) * ST + k * 32 + quad * 8];
        xacc[ch][j] = __builtin_amdgcn_mfma_f32_16x16x32_bf16(a, b, xacc[ch][j], 0, 0, 0);
      }
    }
    hcur = hnext;
  }

  // ---- LN stats ----
  float ssum[4] = {0,0,0,0}, ssq[4] = {0,0,0,0};
#pragma unroll
  for (int ch = 0; ch < 12; ch++)
    for (int j = 0; j < TPW; j++)
      for (int t = 0; t < 4; t++) { float v = xacc[ch][j][t]; ssum[t] += v; ssq[t] += v * v; }
  for (int m = 1; m <= 8; m <<= 1)
    for (int t = 0; t < 4; t++) { ssum[t] += __shfl_xor(ssum[t], m); ssq[t] += __shfl_xor(ssq[t], m); }
  if (l15 == 0)
    for (int t = 0; t < 4; t++) {
      atomicAdd(&stats[m2 * 16 + quad * 4 + t][0], ssum[t]);
      atomicAdd(&stats[m2 * 16 + quad * 4 + t][1], ssq[t]);
    }
  __syncthreads();
  if (tid < NP) {
    float mu = stats[tid][0] * (1.f / 768.f);
    float var = stats[tid][1] * (1.f / 768.f) - mu * mu;
    bc[tid][0] = mu; bc[tid][1] = rsqrtf(fmaxf(var, 0.f) + 1e-5f);
  }
  __syncthreads();

  // ---- LN + relu + write X ----
#pragma unroll
  for (int ch = 0; ch < 12; ch++)
    for (int j = 0; j < TPW; j++)
      for (int t = 0; t < 4; t++) {
        int row = m2 * 16 + quad * 4 + t;
        if (row < n) {
          int d = ch * 64 + (nt20 + j) * 16 + l15;
          float v = fmaxf((xacc[ch][j][t] - bc[row][0]) * bc[row][1] * lg[d] + lb[d], 0.f);
          X[((size_t)g * n + row) * 768 + d] = f2bf(v);
        }
      }
}

template<int NP>
__global__ void __launch_bounds__(512) fused_l2(const u16* __restrict__ adjG, const u16* __restrict__ H,
                                                const float* __restrict__ lng, const float* __restrict__ lnb,
                                                u16* __restrict__ Xmean, int n, float inv,
                                                const float* __restrict__ uvg, const float* __restrict__ cbuf,
                                                float* __restrict__ pOut, float* __restrict__ qOut)
{
  constexpr int ST = 72;
  constexpr int TPW = (NP == 64) ? 2 : 1;
  __shared__ __attribute__((aligned(16))) u16 adjb[NP * ST];
  __shared__ __attribute__((aligned(16))) u16 HT[2][64 * ST];
  __shared__ float stats[NP][2];
  __shared__ float bc[NP][2];
  __shared__ float colsum[768];
  __shared__ float lg[768], lb[768];
  __shared__ float pr[8][2];

  int g = blockIdx.x;
  int tid = threadIdx.x, lane = tid & 63, w = tid >> 6;
  int l15 = lane & 15, quad = lane >> 4;

  for (int i = tid; i < 768; i += 512) { lg[i] = lng[i]; lb[i] = lnb[i]; colsum[i] = 0.f; }
  if (tid < NP) { stats[tid][0] = 0.f; stats[tid][1] = 0.f; }
  if (tid * 8 < NP * NP) {
    int row = (tid * 8) / NP, c0 = (tid * 8) % NP;
    uint4 v = *(const uint4*)(adjG + (size_t)g * NP * NP + row * NP + c0);
    *(uint4*)&adjb[row * ST + c0] = v;
  }

  int m2, nt20;
  if (NP == 64) { m2 = w & 3; nt20 = (w >> 2) * 2; }
  else          { m2 = w & 1; nt20 = w >> 1; }

  float4v xacc[12][TPW];
#pragma unroll
  for (int ch = 0; ch < 12; ch++) for (int j = 0; j < TPW; j++) xacc[ch][j] = (float4v){0.f,0.f,0.f,0.f};

  int hj  = tid & (NP - 1);
  int hseg= (NP == 64) ? w : ((tid >> 5) & 7);
  bool hact = (NP == 64) ? true : (tid < NP * 8);
  const u16* hbase = H + ((size_t)g * n + hj) * 768 + hseg * 8;

  uint4 hcur = {0,0,0,0};
  if (hact && hj < n) hcur = *(const uint4*)(hbase);

  __syncthreads();   // adjb + colsum/stats init visible

#pragma unroll
  for (int ch = 0; ch < 12; ch++) {
    uint4 hnext = {0,0,0,0};
    if (ch < 11 && hact && hj < n) hnext = *(const uint4*)(hbase + (ch + 1) * 64);
    u16* htb = HT[ch & 1];
    if (hact) {
      const u16* ep = (const u16*)&hcur;
      for (int i = 0; i < 8; i++) htb[(hseg * 8 + i) * ST + hj] = ep[i];
    }
    __syncthreads();
    for (int k = 0; k < NP / 32; k++) {
      short8 a = *(const short8*)&adjb[(m2 * 16 + l15) * ST + k * 32 + quad * 8];
      for (int j = 0; j < TPW; j++) {
        short8 b = *(const short8*)&htb[((nt20 + j) * 16 + l15) * ST + k * 32 + quad * 8];
        xacc[ch][j] = __builtin_amdgcn_mfma_f32_16x16x32_bf16(a, b, xacc[ch][j], 0, 0, 0);
      }
    }
    hcur = hnext;
  }

  float ssum[4] = {0,0,0,0}, ssq[4] = {0,0,0,0};
#pragma unroll
  for (int ch = 0; ch < 12; ch++)
    for (int j = 0; j < TPW; j++)
      for (int t = 0; t < 4; t++) { float v = xacc[ch][j][t]; ssum[t] += v; ssq[t] += v * v; }
  for (int m = 1; m <= 8; m <<= 1)
    for (int t = 0; t < 4; t++) { ssum[t] += __shfl_xor(ssum[t], m); ssq[t] += __shfl_xor(ssq[t], m); }
  if (l15 == 0)
    for (int t = 0; t < 4; t++) {
      atomicAdd(&stats[m2 * 16 + quad * 4 + t][0], ssum[t]);
      atomicAdd(&stats[m2 * 16 + quad * 4 + t][1], ssq[t]);
    }
  __syncthreads();
  if (tid < NP) {
    float mu = stats[tid][0] * (1.f / 768.f);
    float var = stats[tid][1] * (1.f / 768.f) - mu * mu;
    bc[tid][0] = mu; bc[tid][1] = rsqrtf(fmaxf(var, 0.f) + 1e-5f);
  }
  __syncthreads();

#pragma unroll
  for (int ch = 0; ch < 12; ch++)
    for (int j = 0; j < TPW; j++)
      for (int t = 0; t < 4; t++) {
        int row = m2 * 16 + quad * 4 + t;
        int d = ch * 64 + (nt20 + j) * 16 + l15;
        float v = fmaxf((xacc[ch][j][t] - bc[row][0]) * bc[row][1] * lg[d] + lb[d], 0.f);
        float vm = (row < n) ? v : 0.f;
        vm += __shfl_xor(vm, 16);
        vm += __shfl_xor(vm, 32);
        if (quad == 0) atomicAdd(&colsum[d], vm);
      }
  __syncthreads();
  if (tid < 384)
    ((u32*)Xmean)[(size_t)g * 384 + tid] = pack2(colsum[tid * 2] * inv, colsum[tid * 2 + 1] * inv);

  // ---- optional: rank-1 bias terms for the next graph level, from the mean row ----
  if (pOut) {
    float pp = 0.f, qq = 0.f;
    if (tid < 384) {
      float x0 = colsum[tid * 2] * inv, x1 = colsum[tid * 2 + 1] * inv;
      pp = x0 * uvg[tid * 2] + x1 * uvg[tid * 2 + 1];
      qq = x0 * uvg[768 + tid * 2] + x1 * uvg[768 + tid * 2 + 1];
    }
    for (int m = 1; m <= 32; m <<= 1) { pp += __shfl_xor(pp, m); qq += __shfl_xor(qq, m); }
    if (lane == 0) { pr[w][0] = pp; pr[w][1] = qq; }
    __syncthreads();
    if (tid == 0) {
      float sp = 0.f, sq = 0.f;
      for (int i = 0; i < 8; i++) { sp += pr[i][0]; sq += pr[i][1]; }
      pOut[g] = sp + cbuf[0]; qOut[g] = sq;
    }
  }
}

// ---------- concat: y = [bf2f(Xm) ; fgs] fp32 (in d_out) ----------
__global__ void __launch_bounds__(384) concat_y(const u16* __restrict__ Xm,
                                                const float* __restrict__ fgs, float* __restrict__ yout)
{
  int b = blockIdx.x, tid = threadIdx.x;
  u32 u = ((const u32*)Xm)[(size_t)b * 384 + tid];
  int d0 = tid * 2;
  yout[(size_t)b * 1536 + d0]     = bflo(u);
  yout[(size_t)b * 1536 + d0 + 1] = bfhi(u);
  yout[(size_t)b * 1536 + 768 + d0]     = fgs[(size_t)b * 768 + d0];
  yout[(size_t)b * 1536 + 768 + d0 + 1] = fgs[(size_t)b * 768 + d0 + 1];
}

// ---------- classifier ----------
__global__ void __launch_bounds__(256) fc1_relu(const float* __restrict__ yout,
                                                const float* __restrict__ fc1w, const float* __restrict__ fc1b,
                                                float* __restrict__ h)
{
  int o = blockIdx.x * 4 + (threadIdx.x >> 6);
  int lane = threadIdx.x & 63;
  float acc[16];
  for (int b = 0; b < 16; b++) acc[b] = 0.f;
  const float4* wr = (const float4*)(fc1w + (size_t)o * 1536);
  for (int k4 = lane; k4 < 384; k4 += 64) {
    float4 wv = wr[k4];
    for (int b = 0; b < 16; b++) {
      float4 yv = ((const float4*)(yout + (size_t)b * 1536))[k4];
      acc[b] += wv.x * yv.x + wv.y * yv.y + wv.z * yv.z + wv.w * yv.w;
    }
  }
  for (int m = 1; m <= 32; m <<= 1)
    for (int b = 0; b < 16; b++) acc[b] += __shfl_xor(acc[b], m);
  if (lane < 16) h[(size_t)lane * 768 + o] = fmaxf(acc[lane] + fc1b[o], 0.f);
}

__global__ void __launch_bounds__(256) fc2_out(const float* __restrict__ h,
                                               const float* __restrict__ fc2w, const float* __restrict__ fc2b,
                                               float* __restrict__ logits)
{
  int o = blockIdx.x * 4 + (threadIdx.x >> 6);
  int lane = threadIdx.x & 63;
  float acc[16];
  for (int b = 0; b < 16; b++) acc[b] = 0.f;
  const float4* wr = (const float4*)(fc2w + (size_t)o * 768);
  for (int k4 = lane; k4 < 192; k4 += 64) {
    float4 wv = wr[k4];
    for (int b = 0; b < 16; b++) {
      float4 hv = ((const float4*)(h + (size_t)b * 768))[k4];
      acc[b] += wv.x * hv.x + wv.y * hv.y + wv.z * hv.z + wv.w * hv.w;
    }
  }
  for (int m = 1; m <= 32; m <<= 1)
    for (int b = 0; b < 16; b++) acc[b] += __shfl_xor(acc[b], m);
  if (lane < 16) logits[(size_t)lane * 400 + o] = acc[lane] + fc2b[o];
}

// ---------- launch ----------
extern "C" void kernel_launch(void* const* d_in, const int* in_sizes, int n_in,
                              void* d_out, int out_size, void* d_ws, size_t ws_size,
                              hipStream_t stream) {
  const float* feats = (const float*)d_in[0];
  const float* fgs   = (const float*)d_in[1];
  const float* wq_w  = (const float*)d_in[3];
  const float* wq_b  = (const float*)d_in[4];
  const float* wk_w  = (const float*)d_in[5];
  const float* wk_b  = (const float*)d_in[6];
  const float* gcn_w = (const float*)d_in[7];
  const float* ln_g  = (const float*)d_in[8];
  const float* ln_b  = (const float*)d_in[9];
  const float* fc1_w = (const float*)d_in[10];
  const float* fc1_b = (const float*)d_in[11];
  const float* fc2_w = (const float*)d_in[12];
  const float* fc2_b = (const float*)d_in[13];
  float* out  = (float*)d_out;
  float* yout = out + 16 * 400;               // y region: [16][1536] fp32

  char* ws = (char*)d_ws;
  size_t off = 0;
  auto alloc = [&](size_t b){ size_t r = off; off = (off + b + 255) & ~(size_t)255; return r; };
  // persistent
  u16*  QHB    = (u16*) (ws + alloc((size_t)1536 * 768 * 2));    // [Wqk^T; gcn0^T] bf16
  u16*  gcnT1  = (u16*) (ws + alloc((size_t)768 * 768 * 2));
  u16*  WqT    = (u16*) (ws + alloc((size_t)768 * 768 * 2));
  u16*  WkT    = (u16*) (ws + alloc((size_t)768 * 768 * 2));
  float* uv    = (float*)(ws + alloc((size_t)1536 * 4));
  float* cbuf  = (float*)(ws + alloc((size_t)4));
  u16*  Abf    = (u16*) (ws + alloc((size_t)25600 * 768 * 2));   // feats pre-converted to bf16
  float* pObj  = (float*)(ws + alloc((size_t)25600 * 4));
  float* qObj  = (float*)(ws + alloc((size_t)25600 * 4));
  float* pF    = (float*)(ws + alloc((size_t)512 * 4));
  float* qF    = (float*)(ws + alloc((size_t)512 * 4));
  u16*  Xf     = (u16*) (ws + alloc((size_t)512 * 768 * 2));
  u16*  QHf    = (u16*) (ws + alloc((size_t)512 * 1536 * 2));
  u16*  X1f    = (u16*) (ws + alloc((size_t)512 * 768 * 2));
  u16*  H2f    = (u16*) (ws + alloc((size_t)512 * 768 * 2));
  u16*  adjFb  = (u16*) (ws + alloc((size_t)16 * 32 * 32 * 2));
  u16*  Xm     = (u16*) (ws + alloc((size_t)16 * 768 * 2));
  float* hbuf  = (float*)(ws + alloc((size_t)16 * 768 * 4));
  size_t base = off;

  // per-chunk: QHc [R][1536] + X1c [R][768] + adjGc [GC][64][64] bf16 (H2c aliases QHc)
  auto need = [&](int GC){
    size_t R = (size_t)GC * 50;
    return base + R * 1536 * 2 + 512 + R * 768 * 2 + 512 + (size_t)GC * 64 * 64 * 2 + 512;
  };
  int GC = 64;
  if (need(512) <= ws_size) GC = 512;
  else if (need(256) <= ws_size) GC = 256;
  else if (need(128) <= ws_size) GC = 128;
  int R = GC * 50;
  size_t off2 = base;
  auto alloc2 = [&](size_t b){ size_t r = off2; off2 = (off2 + b + 255) & ~(size_t)255; return r; };
  u16* QHc   = (u16*)(ws + alloc2((size_t)R * 1536 * 2));
  u16* X1c   = (u16*)(ws + alloc2((size_t)R * 768 * 2));
  u16* adjGc = (u16*)(ws + alloc2((size_t)GC * 64 * 64 * 2));
  u16* H2c   = QHc;                      // QHc dead after fused_l1

  // ---- prep ----
  prep_w<<<dim3(24, 24, 4), dim3(32, 8), 0, stream>>>(wq_w, wk_w, gcn_w, WqT, WkT,
                                                      QHB + (size_t)768 * 768, gcnT1);
  prep_uv2<<<25, 256, 0, stream>>>(wq_w, wk_w, wq_b, wk_b, uv, cbuf);
  // QHB rows 0-767: C[d'][d] = sum_o WkT[d'][o]*WqT[d][o] = Wqk[d][d']  (gemm1's B layout)
  gemm_bt<<<dim3(6, 6), 256, 0, stream>>>(WkT, WqT, nullptr, QHB, 768, 768, 768);
  conv_pq<<<3200, 256, 0, stream>>>(feats, Abf, uv, cbuf, pObj, qObj);

  // ---- object-level graph (512 graphs of n=50), chunked ----
  int nchunks = 512 / GC;
  for (int c = 0; c < nchunks; c++) {
    const u16* fc = Abf + (size_t)c * GC * 50 * 768;
    gemm_bt<<<dim3(R / 128, 12), 256, 0, stream>>>(fc, QHB, nullptr, QHc, R, 1536, 768);
    fused_l1<64><<<GC, 512, 0, stream>>>(QHc, fc, pObj + (size_t)c * GC * 50, qObj + (size_t)c * GC * 50,
                                         ln_g, ln_b, adjGc, X1c, 50);
    gemm_bt<<<dim3(R / 128, 6), 256, 0, stream>>>(X1c, gcnT1, nullptr, H2c, R, 768, 768);
    fused_l2<64><<<GC, 512, 0, stream>>>(adjGc, H2c, ln_g + 768, ln_b + 768,
                                         Xf + (size_t)c * GC * 768, 50, 1.f / 50.f,
                                         uv, cbuf, pF + (size_t)c * GC, qF + (size_t)c * GC);
  }

  // ---- frame-level graph (16 graphs of n=32) ----
  gemm_bt<<<dim3(4, 12), 256, 0, stream>>>(Xf, QHB, nullptr, QHf, 512, 1536, 768);
  fused_l1<32><<<16, 512, 0, stream>>>(QHf, Xf, pF, qF, ln_g, ln_b, adjFb, X1f, 32);
  gemm_bt<<<dim3(4, 6), 256, 0, stream>>>(X1f, gcnT1, nullptr, H2f, 512, 768, 768);
  fused_l2<32><<<16, 512, 0, stream>>>(adjFb, H2f, ln_g + 768, ln_b + 768, Xm, 32, 1.f / 32.f,
                                       uv, cbuf, nullptr, nullptr);

  // ---- head ----
  concat_y<<<16, 384, 0, stream>>>(Xm, fgs, yout);
  fc1_relu<<<192, 256, 0, stream>>>(yout, fc1_w, fc1_b, hbuf);
  fc2_out<<<100, 256, 0, stream>>>(hbuf, fc2_w, fc2_b, out);
}

// Round 8
// 494.848 us; speedup vs baseline: 1.3533x; 1.0302x over previous
//
#include <hip/hip_runtime.h>
#include <hip/hip_bf16.h>

typedef unsigned short u16;
typedef unsigned int   u32;
typedef __attribute__((ext_vector_type(8))) short short8;
typedef __attribute__((ext_vector_type(4))) float float4v;

// ---------- helpers ----------
__device__ __forceinline__ float bf2f(u16 u){ union{u32 i; float f;} c; c.i = ((u32)u) << 16; return c.f; }
__device__ __forceinline__ float bflo(u32 u){ union{u32 i; float f;} c; c.i = u << 16; return c.f; }
__device__ __forceinline__ float bfhi(u32 u){ union{u32 i; float f;} c; c.i = u & 0xFFFF0000u; return c.f; }
__device__ __forceinline__ u16 f2bf(float f){
  union{float f; u32 i;} c; c.f = f; u32 x = c.i;
  return (u16)((x + 0x7FFFu + ((x >> 16) & 1u)) >> 16);   // RNE
}
// packed f32x2 -> bf16x2, RNE (v_cvt_pk_bf16_f32)
__device__ __forceinline__ u32 pack2(float a, float b){
  union { __hip_bfloat162 h; u32 u; } c;
  c.h = __float22bfloat162_rn(float2{a, b});
  return c.u;
}

__device__ __forceinline__ void async16(const void* g, void* l){
  __builtin_amdgcn_global_load_lds((const __attribute__((address_space(1))) void*)g,
                                   (__attribute__((address_space(3))) void*)l, 16, 0, 0);
}

// ---------- prep: all four 768x768 fp32 -> bf16 transposes in ONE launch ----------
// z=0: wq -> WqT ; z=1: wk -> WkT ; z=2: gcn[0] -> QHB rows 768.. ; z=3: gcn[1] -> gcnT1
__global__ void prep_w(const float* __restrict__ wq, const float* __restrict__ wk,
                       const float* __restrict__ gcn,
                       u16* __restrict__ WqT, u16* __restrict__ WkT,
                       u16* __restrict__ QHB768, u16* __restrict__ gcnT1)
{
  __shared__ float tile[32][33];
  int z = blockIdx.z;
  const float* src = (z == 0) ? wq : (z == 1) ? wk : gcn + (size_t)(z - 2) * 589824;
  u16* dst = (z == 0) ? WqT : (z == 1) ? WkT : (z == 2) ? QHB768 : gcnT1;
  int r0 = blockIdx.y * 32, c0 = blockIdx.x * 32;
  int tx = threadIdx.x, ty = threadIdx.y;           // 32 x 8
  for (int i = 0; i < 32; i += 8) tile[ty + i][tx] = src[(size_t)(r0 + ty + i) * 768 + c0 + tx];
  __syncthreads();
  for (int i = 0; i < 32; i += 8) dst[(size_t)(c0 + ty + i) * 768 + r0 + tx] = f2bf(tile[tx][ty + i]);
}

// ---------- prep: u = Wq^T bk (uv[0:768]), v = Wk^T bq (uv[768:1536]), cbuf[0] = bq.bk ----------
__global__ void __launch_bounds__(256) prep_uv2(const float* __restrict__ wq, const float* __restrict__ wk,
                                                const float* __restrict__ wqb, const float* __restrict__ wkb,
                                                float* __restrict__ uv, float* __restrict__ cbuf)
{
  __shared__ float red[4][64];
  __shared__ float r2[256];
  int b = blockIdx.x, tid = threadIdx.x;
  if (b < 24) {
    const float* w  = (b < 12) ? wq : wk;
    const float* bs = (b < 12) ? wkb : wqb;
    int out = (b % 12) * 64 + (tid & 63);
    int oq = tid >> 6;
    float a = 0.f;
    for (int o = oq * 192; o < oq * 192 + 192; o++) a += w[(size_t)o * 768 + out] * bs[o];
    red[oq][tid & 63] = a;
    __syncthreads();
    if (tid < 64)
      uv[((b < 12) ? 0 : 768) + (b % 12) * 64 + tid] = red[0][tid] + red[1][tid] + red[2][tid] + red[3][tid];
  } else {
    float a = 0.f;
    for (int o = tid; o < 768; o += 256) a += wqb[o] * wkb[o];
    r2[tid] = a; __syncthreads();
    if (tid == 0) { float s = 0.f; for (int i = 0; i < 256; i++) s += r2[i]; cbuf[0] = s; }
  }
}

// ---------- feats fp32 -> bf16 + per-row p,q (fused: zero extra global traffic) ----------
__global__ void __launch_bounds__(256) conv_pq(const float* __restrict__ src, u16* __restrict__ dst,
                                               const float* __restrict__ uv, const float* __restrict__ cbuf,
                                               float* __restrict__ p, float* __restrict__ q)
{
  __shared__ float us[768], vs[768];
  int tid = threadIdx.x, lane = tid & 63;
  for (int i = tid; i < 768; i += 256) { us[i] = uv[i]; vs[i] = uv[768 + i]; }
  __syncthreads();
  size_t rbase = (size_t)blockIdx.x * 8;
  int row = tid >> 5;                 // 0..7 (two rows per wave)
  int c3  = (tid & 31) * 3;           // starting octet within row
  const float* s = src + (rbase + row) * 768 + (size_t)c3 * 8;
  u16* d = dst + (rbase + row) * 768 + (size_t)c3 * 8;
  float ap = 0.f, aq = 0.f;
#pragma unroll
  for (int j = 0; j < 3; j++) {
    float4 a = ((const float4*)s)[j * 2];
    float4 b = ((const float4*)s)[j * 2 + 1];
    uint4 o = { pack2(a.x, a.y), pack2(a.z, a.w), pack2(b.x, b.y), pack2(b.z, b.w) };
    ((uint4*)d)[j] = o;
    const float* uu = &us[(c3 + j) * 8];
    const float* vv = &vs[(c3 + j) * 8];
    ap += a.x*uu[0] + a.y*uu[1] + a.z*uu[2] + a.w*uu[3] + b.x*uu[4] + b.y*uu[5] + b.z*uu[6] + b.w*uu[7];
    aq += a.x*vv[0] + a.y*vv[1] + a.z*vv[2] + a.w*vv[3] + b.x*vv[4] + b.y*vv[5] + b.z*vv[6] + b.w*vv[7];
  }
  for (int m = 1; m <= 16; m <<= 1) { ap += __shfl_xor(ap, m); aq += __shfl_xor(aq, m); }
  if ((lane & 31) == 0) {
    p[rbase + row] = ap + cbuf[0];
    q[rbase + row] = aq;
  }
}

// ---------- main GEMM: C[m][n] = sum_k A[m][k]*B[n][k] + bias[n] ----------
// 128x128 tile, BK=64, round-3 verified structure (chunk-XOR swizzle, conflict-free).
__global__ void __launch_bounds__(256) gemm_bt(const u16* __restrict__ A, const u16* __restrict__ Bw,
                                               const float* __restrict__ bias, u16* __restrict__ C,
                                               int M, int N, int K)
{
  __shared__ __attribute__((aligned(16))) u16 As[128 * 64];
  __shared__ __attribute__((aligned(16))) u16 Bs[128 * 64];
  int tid = threadIdx.x, lane = tid & 63, wid = tid >> 6;
  int wm = wid >> 1, wn = wid & 1;
  size_t m0 = (size_t)blockIdx.x * 128, n0 = (size_t)blockIdx.y * 128;

  float4v acc[4][4];
  for (int r = 0; r < 4; r++) for (int c = 0; c < 4; c++) acc[r][c] = (float4v){0.f, 0.f, 0.f, 0.f};

  int srow8  = lane >> 3;
  int schunk = (lane & 7) ^ srow8;
  const u16* gA[4]; const u16* gB[4];
  u16* lA[4]; u16* lB[4];
#pragma unroll
  for (int j = 0; j < 4; j++) {
    int r = 32 * wid + 8 * j + srow8;
    gA[j] = A  + (m0 + r) * (size_t)K + schunk * 8;
    gB[j] = Bw + (n0 + r) * (size_t)K + schunk * 8;
    lA[j] = &As[(32 * wid + 8 * j) * 64];
    lB[j] = &Bs[(32 * wid + 8 * j) * 64];
  }

  int l15 = lane & 15, quad = lane >> 4;
  int s0 = quad ^ (l15 & 7);

  for (int kt = 0; kt < K; kt += 64) {
#pragma unroll
    for (int j = 0; j < 4; j++) {
      async16(gA[j] + kt, lA[j]);
      async16(gB[j] + kt, lB[j]);
    }
    __syncthreads();
#pragma unroll
    for (int ks = 0; ks < 2; ks++) {
      int so = (s0 ^ (ks << 2)) * 8;
      short8 af[4], bfr[4];
#pragma unroll
      for (int r = 0; r < 4; r++) af[r]  = *(const short8*)&As[(wm * 64 + r * 16 + l15) * 64 + so];
#pragma unroll
      for (int c = 0; c < 4; c++) bfr[c] = *(const short8*)&Bs[(wn * 64 + c * 16 + l15) * 64 + so];
#pragma unroll
      for (int r = 0; r < 4; r++)
#pragma unroll
        for (int c = 0; c < 4; c++)
          acc[r][c] = __builtin_amdgcn_mfma_f32_16x16x32_bf16(af[r], bfr[c], acc[r][c], 0, 0, 0);
    }
    __syncthreads();
  }

  int quad4 = quad * 4;
  for (int c = 0; c < 4; c++) {
    int n = (int)n0 + wn * 64 + c * 16 + l15;
    float bv = bias ? bias[n] : 0.f;
    for (int r = 0; r < 4; r++) {
      size_t mbase = m0 + wm * 64 + r * 16 + quad4;
      for (int t = 0; t < 4; t++)
        C[(mbase + t) * (size_t)N + n] = f2bf(acc[r][c][t] + bv);
    }
  }
}

// ================= fused per-graph adjacency kernels =================
// TH rows (stride 1536): [0,768)=T = x.Wqk, [768,1536)=H1. AR = raw x rows (stride 768).
// S_ij = T_i . x_j + p_i + q_j. Stage 1 now uses gemm-style COALESCED LDS staging
// (global_load_lds + chunk-XOR swizzle, same math as gemm_bt — the old direct loads were
// 16-row-strided gathers). OOB tile rows are clamped; cols>=n force-zeroed (cok), rows>=n
// masked at every consumer — same guarantees as the zero-fill version.

template<int NP>
__global__ void __launch_bounds__(512) fused_l1(const u16* __restrict__ TH, const u16* __restrict__ AR,
                                                const float* __restrict__ pb, const float* __restrict__ qb,
                                                const float* __restrict__ lng, const float* __restrict__ lnb,
                                                u16* __restrict__ adjG, u16* __restrict__ X, int n, int Mtot)
{
  constexpr int ST = 72;
  constexpr int TPW = (NP == 64) ? 2 : 1;
  constexpr int SR = NP;                       // stage-1 tile rows (64 or 32)
  __shared__ __attribute__((aligned(16))) u16 adjb[NP * ST];
  __shared__ __attribute__((aligned(16))) u16 HT[2][64 * ST];
  __shared__ __attribute__((aligned(16))) u16 As1[SR * 64];
  __shared__ __attribute__((aligned(16))) u16 Bs1[SR * 64];
  __shared__ float rsum[NP];
  __shared__ float stats[NP][2];
  __shared__ float bc[NP][2];
  __shared__ float ps[NP], qs[NP];
  __shared__ float lg[768], lb[768];

  int g = blockIdx.x;
  int tid = threadIdx.x, lane = tid & 63, w = tid >> 6;
  int l15 = lane & 15, quad = lane >> 4;

  for (int i = tid; i < 768; i += 512) { lg[i] = lng[i]; lb[i] = lnb[i]; }
  if (tid < NP) {
    rsum[tid] = 0.f; stats[tid][0] = 0.f; stats[tid][1] = 0.f;
    ps[tid] = (tid < n) ? pb[(size_t)g * n + tid] : 0.f;
    qs[tid] = (tid < n) ? qb[(size_t)g * n + tid] : 0.f;
  }
  __syncthreads();

  // ---- stage 1: S = T @ x^T, gemm-style LDS staging ----
  int mt, nt0; bool s_act;
  if (NP == 64) { mt = w & 3; nt0 = (w >> 2) * 2; s_act = true; }
  else          { mt = w & 1; nt0 = w >> 1;       s_act = (w < 4); }

  // staging addresses: wave covers 8 rows; lane l -> row +(l>>3), src chunk (l&7)^(l>>3)
  int srow8  = lane >> 3;
  int schunk = (lane & 7) ^ srow8;
  int trow   = (NP == 64) ? (8 * w + srow8) : (8 * (w & 3) + srow8);
  size_t grow = (size_t)g * n + trow;
  if (grow >= (size_t)Mtot) grow = Mtot - 1;   // clamp (garbage masked downstream)
  const u16* gA1 = TH + grow * 1536 + schunk * 8;
  const u16* gB1 = AR + grow * 768  + schunk * 8;
  u16* lA1 = &As1[((NP == 64) ? 8 * w : 8 * (w & 3)) * 64];
  u16* lB1 = &Bs1[((NP == 64) ? 8 * w : 8 * (w & 3)) * 64];
  int s0 = quad ^ (l15 & 7);

  float4v sacc[TPW];
  for (int j = 0; j < TPW; j++) sacc[j] = (float4v){0.f, 0.f, 0.f, 0.f};

  for (int kt = 0; kt < 768; kt += 64) {
    if (NP == 64) {
      async16(gA1 + kt, lA1);
      async16(gB1 + kt, lB1);
    } else {
      if (w < 4) async16(gA1 + kt, lA1);
      else       async16(gB1 + kt, lB1);
    }
    __syncthreads();
    if (s_act) {
#pragma unroll
      for (int ks = 0; ks < 2; ks++) {
        int so = (s0 ^ (ks << 2)) * 8;
        short8 a = *(const short8*)&As1[(mt * 16 + l15) * 64 + so];
#pragma unroll
        for (int j = 0; j < TPW; j++) {
          short8 b = *(const short8*)&Bs1[((nt0 + j) * 16 + l15) * 64 + so];
          sacc[j] = __builtin_amdgcn_mfma_f32_16x16x32_bf16(a, b, sacc[j], 0, 0, 0);
        }
      }
    }
    __syncthreads();
  }

  if (s_act) {
    // add rank-1 bias terms; force cols >= n to EXACT zero (also kills clamp garbage)
    for (int j = 0; j < TPW; j++) {
      int col = (nt0 + j) * 16 + l15;
      bool cok = col < n;
      for (int t = 0; t < 4; t++) {
        int row = mt * 16 + quad * 4 + t;
        sacc[j][t] = cok ? (sacc[j][t] + ps[row] + qs[col]) : 0.f;
      }
    }
    // partial row sums of S^2 (reduce over the 16 cols held across l15 lanes)
    for (int t = 0; t < 4; t++) {
      float s = 0.f;
      for (int j = 0; j < TPW; j++) { float v = sacc[j][t]; s += v * v; }
      s += __shfl_xor(s, 1); s += __shfl_xor(s, 2); s += __shfl_xor(s, 4); s += __shfl_xor(s, 8);
      if (l15 == 0) atomicAdd(&rsum[mt * 16 + quad * 4 + t], s);
    }
  }
  __syncthreads();
  if (tid < NP) rsum[tid] = 1.0f / fmaxf(rsum[tid], 1e-12f);
  __syncthreads();
  if (s_act) {
    u16* gadj = adjG + (size_t)g * NP * NP;
    for (int j = 0; j < TPW; j++)
      for (int t = 0; t < 4; t++) {
        int row = mt * 16 + quad * 4 + t, col = (nt0 + j) * 16 + l15;
        float v = sacc[j][t];
        u16 b = f2bf(v * v * rsum[row]);
        adjb[row * ST + col] = b;
        gadj[row * NP + col] = b;
      }
  }
  __syncthreads();

  // ---- stage 2: X = adj @ H1, 12 chunks of 64 d-cols ----
  int m2, nt20;
  if (NP == 64) { m2 = w & 3; nt20 = (w >> 2) * 2; }
  else          { m2 = w & 1; nt20 = w >> 1; }

  float4v xacc[12][TPW];
#pragma unroll
  for (int ch = 0; ch < 12; ch++) for (int j = 0; j < TPW; j++) xacc[ch][j] = (float4v){0.f,0.f,0.f,0.f};

  int hj  = tid & (NP - 1);
  int hseg= (NP == 64) ? w : ((tid >> 5) & 7);
  bool hact = (NP == 64) ? true : (tid < NP * 8);
  const u16* hbase = TH + ((size_t)g * n + hj) * 1536 + 768 + hseg * 8;

  uint4 hcur = {0,0,0,0};
  if (hact && hj < n) hcur = *(const uint4*)(hbase);

#pragma unroll
  for (int ch = 0; ch < 12; ch++) {
    uint4 hnext = {0,0,0,0};
    if (ch < 11 && hact && hj < n) hnext = *(const uint4*)(hbase + (ch + 1) * 64);
    u16* htb = HT[ch & 1];
    if (hact) {
      const u16* ep = (const u16*)&hcur;
      for (int i = 0; i < 8; i++) htb[(hseg * 8 + i) * ST + hj] = ep[i];
    }
    __syncthreads();
    for (int k = 0; k < NP / 32; k++) {
      short8 a = *(const short8*)&adjb[(m2 * 16 + l15) * ST + k * 32 + quad * 8];
      for (int j = 0; j < TPW; j++) {
        short8 b = *(const short8*)&htb[((nt20 + j) * 16 + l15) * ST + k * 32 + quad * 8];
        xacc[ch][j] = __builtin_amdgcn_mfma_f32_16x16x32_bf16(a, b, xacc[ch][j], 0, 0, 0);
      }
    }
    hcur = hnext;
  }

  // ---- LN stats ----
  float ssum[4] = {0,0,0,0}, ssq[4] = {0,0,0,0};
#pragma unroll
  for (int ch = 0; ch < 12; ch++)
    for (int j = 0; j < TPW; j++)
      for (int t = 0; t < 4; t++) { float v = xacc[ch][j][t]; ssum[t] += v; ssq[t] += v * v; }
  for (int m = 1; m <= 8; m <<= 1)
    for (int t = 0; t < 4; t++) { ssum[t] += __shfl_xor(ssum[t], m); ssq[t] += __shfl_xor(ssq[t], m); }
  if (l15 == 0)
    for (int t = 0; t < 4; t++) {
      atomicAdd(&stats[m2 * 16 + quad * 4 + t][0], ssum[t]);
      atomicAdd(&stats[m2 * 16 + quad * 4 + t][1], ssq[t]);
    }
  __syncthreads();
  if (tid < NP) {
    float mu = stats[tid][0] * (1.f / 768.f);
    float var = stats[tid][1] * (1.f / 768.f) - mu * mu;
    bc[tid][0] = mu; bc[tid][1] = rsqrtf(fmaxf(var, 0.f) + 1e-5f);
  }
  __syncthreads();

  // ---- LN + relu + write X ----
#pragma unroll
  for (int ch = 0; ch < 12; ch++)
    for (int j = 0; j < TPW; j++)
      for (int t = 0; t < 4; t++) {
        int row = m2 * 16 + quad * 4 + t;
        if (row < n) {
          int d = ch * 64 + (nt20 + j) * 16 + l15;
          float v = fmaxf((xacc[ch][j][t] - bc[row][0]) * bc[row][1] * lg[d] + lb[d], 0.f);
          X[((size_t)g * n + row) * 768 + d] = f2bf(v);
        }
      }
}

template<int NP>
__global__ void __launch_bounds__(512) fused_l2(const u16* __restrict__ adjG, const u16* __restrict__ H,
                                                const float* __restrict__ lng, const float* __restrict__ lnb,
                                                u16* __restrict__ Xmean, int n, float inv,
                                                const float* __restrict__ uvg, const float* __restrict__ cbuf,
                                                float* __restrict__ pOut, float* __restrict__ qOut)
{
  constexpr int ST = 72;
  constexpr int TPW = (NP == 64) ? 2 : 1;
  __shared__ __attribute__((aligned(16))) u16 adjb[NP * ST];
  __shared__ __attribute__((aligned(16))) u16 HT[2][64 * ST];
  __shared__ float stats[NP][2];
  __shared__ float bc[NP][2];
  __shared__ float colsum[768];
  __shared__ float lg[768], lb[768];
  __shared__ float pr[8][2];

  int g = blockIdx.x;
  int tid = threadIdx.x, lane = tid & 63, w = tid >> 6;
  int l15 = lane & 15, quad = lane >> 4;

  for (int i = tid; i < 768; i += 512) { lg[i] = lng[i]; lb[i] = lnb[i]; colsum[i] = 0.f; }
  if (tid < NP) { stats[tid][0] = 0.f; stats[tid][1] = 0.f; }
  if (tid * 8 < NP * NP) {
    int row = (tid * 8) / NP, c0 = (tid * 8) % NP;
    uint4 v = *(const uint4*)(adjG + (size_t)g * NP * NP + row * NP + c0);
    *(uint4*)&adjb[row * ST + c0] = v;
  }

  int m2, nt20;
  if (NP == 64) { m2 = w & 3; nt20 = (w >> 2) * 2; }
  else          { m2 = w & 1; nt20 = w >> 1; }

  float4v xacc[12][TPW];
#pragma unroll
  for (int ch = 0; ch < 12; ch++) for (int j = 0; j < TPW; j++) xacc[ch][j] = (float4v){0.f,0.f,0.f,0.f};

  int hj  = tid & (NP - 1);
  int hseg= (NP == 64) ? w : ((tid >> 5) & 7);
  bool hact = (NP == 64) ? true : (tid < NP * 8);
  const u16* hbase = H + ((size_t)g * n + hj) * 768 + hseg * 8;

  uint4 hcur = {0,0,0,0};
  if (hact && hj < n) hcur = *(const uint4*)(hbase);

  __syncthreads();   // adjb + colsum/stats init visible

#pragma unroll
  for (int ch = 0; ch < 12; ch++) {
    uint4 hnext = {0,0,0,0};
    if (ch < 11 && hact && hj < n) hnext = *(const uint4*)(hbase + (ch + 1) * 64);
    u16* htb = HT[ch & 1];
    if (hact) {
      const u16* ep = (const u16*)&hcur;
      for (int i = 0; i < 8; i++) htb[(hseg * 8 + i) * ST + hj] = ep[i];
    }
    __syncthreads();
    for (int k = 0; k < NP / 32; k++) {
      short8 a = *(const short8*)&adjb[(m2 * 16 + l15) * ST + k * 32 + quad * 8];
      for (int j = 0; j < TPW; j++) {
        short8 b = *(const short8*)&htb[((nt20 + j) * 16 + l15) * ST + k * 32 + quad * 8];
        xacc[ch][j] = __builtin_amdgcn_mfma_f32_16x16x32_bf16(a, b, xacc[ch][j], 0, 0, 0);
      }
    }
    hcur = hnext;
  }

  float ssum[4] = {0,0,0,0}, ssq[4] = {0,0,0,0};
#pragma unroll
  for (int ch = 0; ch < 12; ch++)
    for (int j = 0; j < TPW; j++)
      for (int t = 0; t < 4; t++) { float v = xacc[ch][j][t]; ssum[t] += v; ssq[t] += v * v; }
  for (int m = 1; m <= 8; m <<= 1)
    for (int t = 0; t < 4; t++) { ssum[t] += __shfl_xor(ssum[t], m); ssq[t] += __shfl_xor(ssq[t], m); }
  if (l15 == 0)
    for (int t = 0; t < 4; t++) {
      atomicAdd(&stats[m2 * 16 + quad * 4 + t][0], ssum[t]);
      atomicAdd(&stats[m2 * 16 + quad * 4 + t][1], ssq[t]);
    }
  __syncthreads();
  if (tid < NP) {
    float mu = stats[tid][0] * (1.f / 768.f);
    float var = stats[tid][1] * (1.f / 768.f) - mu * mu;
    bc[tid][0] = mu; bc[tid][1] = rsqrtf(fmaxf(var, 0.f) + 1e-5f);
  }
  __syncthreads();

#pragma unroll
  for (int ch = 0; ch < 12; ch++)
    for (int j = 0; j < TPW; j++)
      for (int t = 0; t < 4; t++) {
        int row = m2 * 16 + quad * 4 + t;
        int d = ch * 64 + (nt20 + j) * 16 + l15;
        float v = fmaxf((xacc[ch][j][t] - bc[row][0]) * bc[row][1] * lg[d] + lb[d], 0.f);
        float vm = (row < n) ? v : 0.f;
        vm += __shfl_xor(vm, 16);
        vm += __shfl_xor(vm, 32);
        if (quad == 0) atomicAdd(&colsum[d], vm);
      }
  __syncthreads();
  if (tid < 384)
    ((u32*)Xmean)[(size_t)g * 384 + tid] = pack2(colsum[tid * 2] * inv, colsum[tid * 2 + 1] * inv);

  // ---- optional: rank-1 bias terms for the next graph level, from the mean row ----
  if (pOut) {
    float pp = 0.f, qq = 0.f;
    if (tid < 384) {
      float x0 = colsum[tid * 2] * inv, x1 = colsum[tid * 2 + 1] * inv;
      pp = x0 * uvg[tid * 2] + x1 * uvg[tid * 2 + 1];
      qq = x0 * uvg[768 + tid * 2] + x1 * uvg[768 + tid * 2 + 1];
    }
    for (int m = 1; m <= 32; m <<= 1) { pp += __shfl_xor(pp, m); qq += __shfl_xor(qq, m); }
    if (lane == 0) { pr[w][0] = pp; pr[w][1] = qq; }
    __syncthreads();
    if (tid == 0) {
      float sp = 0.f, sq = 0.f;
      for (int i = 0; i < 8; i++) { sp += pr[i][0]; sq += pr[i][1]; }
      pOut[g] = sp + cbuf[0]; qOut[g] = sq;
    }
  }
}

// ---------- concat: y = [bf2f(Xm) ; fgs] fp32 (in d_out) ----------
__global__ void __launch_bounds__(384) concat_y(const u16* __restrict__ Xm,
                                                const float* __restrict__ fgs, float* __restrict__ yout)
{
  int b = blockIdx.x, tid = threadIdx.x;
  u32 u = ((const u32*)Xm)[(size_t)b * 384 + tid];
  int d0 = tid * 2;
  yout[(size_t)b * 1536 + d0]     = bflo(u);
  yout[(size_t)b * 1536 + d0 + 1] = bfhi(u);
  yout[(size_t)b * 1536 + 768 + d0]     = fgs[(size_t)b * 768 + d0];
  yout[(size_t)b * 1536 + 768 + d0 + 1] = fgs[(size_t)b * 768 + d0 + 1];
}

// ---------- classifier ----------
__global__ void __launch_bounds__(256) fc1_relu(const float* __restrict__ yout,
                                                const float* __restrict__ fc1w, const float* __restrict__ fc1b,
                                                float* __restrict__ h)
{
  int o = blockIdx.x * 4 + (threadIdx.x >> 6);
  int lane = threadIdx.x & 63;
  float acc[16];
  for (int b = 0; b < 16; b++) acc[b] = 0.f;
  const float4* wr = (const float4*)(fc1w + (size_t)o * 1536);
  for (int k4 = lane; k4 < 384; k4 += 64) {
    float4 wv = wr[k4];
    for (int b = 0; b < 16; b++) {
      float4 yv = ((const float4*)(yout + (size_t)b * 1536))[k4];
      acc[b] += wv.x * yv.x + wv.y * yv.y + wv.z * yv.z + wv.w * yv.w;
    }
  }
  for (int m = 1; m <= 32; m <<= 1)
    for (int b = 0; b < 16; b++) acc[b] += __shfl_xor(acc[b], m);
  if (lane < 16) h[(size_t)lane * 768 + o] = fmaxf(acc[lane] + fc1b[o], 0.f);
}

__global__ void __launch_bounds__(256) fc2_out(const float* __restrict__ h,
                                               const float* __restrict__ fc2w, const float* __restrict__ fc2b,
                                               float* __restrict__ logits)
{
  int o = blockIdx.x * 4 + (threadIdx.x >> 6);
  int lane = threadIdx.x & 63;
  float acc[16];
  for (int b = 0; b < 16; b++) acc[b] = 0.f;
  const float4* wr = (const float4*)(fc2w + (size_t)o * 768);
  for (int k4 = lane; k4 < 192; k4 += 64) {
    float4 wv = wr[k4];
    for (int b = 0; b < 16; b++) {
      float4 hv = ((const float4*)(h + (size_t)b * 768))[k4];
      acc[b] += wv.x * hv.x + wv.y * hv.y + wv.z * hv.z + wv.w * hv.w;
    }
  }
  for (int m = 1; m <= 32; m <<= 1)
    for (int b = 0; b < 16; b++) acc[b] += __shfl_xor(acc[b], m);
  if (lane < 16) logits[(size_t)lane * 400 + o] = acc[lane] + fc2b[o];
}

// ---------- launch ----------
extern "C" void kernel_launch(void* const* d_in, const int* in_sizes, int n_in,
                              void* d_out, int out_size, void* d_ws, size_t ws_size,
                              hipStream_t stream) {
  const float* feats = (const float*)d_in[0];
  const float* fgs   = (const float*)d_in[1];
  const float* wq_w  = (const float*)d_in[3];
  const float* wq_b  = (const float*)d_in[4];
  const float* wk_w  = (const float*)d_in[5];
  const float* wk_b  = (const float*)d_in[6];
  const float* gcn_w = (const float*)d_in[7];
  const float* ln_g  = (const float*)d_in[8];
  const float* ln_b  = (const float*)d_in[9];
  const float* fc1_w = (const float*)d_in[10];
  const float* fc1_b = (const float*)d_in[11];
  const float* fc2_w = (const float*)d_in[12];
  const float* fc2_b = (const float*)d_in[13];
  float* out  = (float*)d_out;
  float* yout = out + 16 * 400;               // y region: [16][1536] fp32

  char* ws = (char*)d_ws;
  size_t off = 0;
  auto alloc = [&](size_t b){ size_t r = off; off = (off + b + 255) & ~(size_t)255; return r; };
  // persistent
  u16*  QHB    = (u16*) (ws + alloc((size_t)1536 * 768 * 2));    // [Wqk^T; gcn0^T] bf16
  u16*  gcnT1  = (u16*) (ws + alloc((size_t)768 * 768 * 2));
  u16*  WqT    = (u16*) (ws + alloc((size_t)768 * 768 * 2));
  u16*  WkT    = (u16*) (ws + alloc((size_t)768 * 768 * 2));
  float* uv    = (float*)(ws + alloc((size_t)1536 * 4));
  float* cbuf  = (float*)(ws + alloc((size_t)4));
  u16*  Abf    = (u16*) (ws + alloc((size_t)25600 * 768 * 2));   // feats pre-converted to bf16
  float* pObj  = (float*)(ws + alloc((size_t)25600 * 4));
  float* qObj  = (float*)(ws + alloc((size_t)25600 * 4));
  float* pF    = (float*)(ws + alloc((size_t)512 * 4));
  float* qF    = (float*)(ws + alloc((size_t)512 * 4));
  u16*  Xf     = (u16*) (ws + alloc((size_t)512 * 768 * 2));
  u16*  QHf    = (u16*) (ws + alloc((size_t)512 * 1536 * 2));
  u16*  X1f    = (u16*) (ws + alloc((size_t)512 * 768 * 2));
  u16*  H2f    = (u16*) (ws + alloc((size_t)512 * 768 * 2));
  u16*  adjFb  = (u16*) (ws + alloc((size_t)16 * 32 * 32 * 2));
  u16*  Xm     = (u16*) (ws + alloc((size_t)16 * 768 * 2));
  float* hbuf  = (float*)(ws + alloc((size_t)16 * 768 * 4));
  size_t base = off;

  // per-chunk: QHc [R][1536] + X1c [R][768] + adjGc [GC][64][64] bf16 (H2c aliases QHc)
  auto need = [&](int GC){
    size_t R = (size_t)GC * 50;
    return base + R * 1536 * 2 + 512 + R * 768 * 2 + 512 + (size_t)GC * 64 * 64 * 2 + 512;
  };
  int GC = 64;
  if (need(512) <= ws_size) GC = 512;
  else if (need(256) <= ws_size) GC = 256;
  else if (need(128) <= ws_size) GC = 128;
  int R = GC * 50;
  size_t off2 = base;
  auto alloc2 = [&](size_t b){ size_t r = off2; off2 = (off2 + b + 255) & ~(size_t)255; return r; };
  u16* QHc   = (u16*)(ws + alloc2((size_t)R * 1536 * 2));
  u16* X1c   = (u16*)(ws + alloc2((size_t)R * 768 * 2));
  u16* adjGc = (u16*)(ws + alloc2((size_t)GC * 64 * 64 * 2));
  u16* H2c   = QHc;                      // QHc dead after fused_l1

  // ---- prep ----
  prep_w<<<dim3(24, 24, 4), dim3(32, 8), 0, stream>>>(wq_w, wk_w, gcn_w, WqT, WkT,
                                                      QHB + (size_t)768 * 768, gcnT1);
  prep_uv2<<<25, 256, 0, stream>>>(wq_w, wk_w, wq_b, wk_b, uv, cbuf);
  // QHB rows 0-767: C[d'][d] = sum_o WkT[d'][o]*WqT[d][o] = Wqk[d][d']  (gemm1's B layout)
  gemm_bt<<<dim3(6, 6), 256, 0, stream>>>(WkT, WqT, nullptr, QHB, 768, 768, 768);
  conv_pq<<<3200, 256, 0, stream>>>(feats, Abf, uv, cbuf, pObj, qObj);

  // ---- object-level graph (512 graphs of n=50), chunked ----
  int nchunks = 512 / GC;
  for (int c = 0; c < nchunks; c++) {
    const u16* fc = Abf + (size_t)c * GC * 50 * 768;
    gemm_bt<<<dim3(R / 128, 12), 256, 0, stream>>>(fc, QHB, nullptr, QHc, R, 1536, 768);
    fused_l1<64><<<GC, 512, 0, stream>>>(QHc, fc, pObj + (size_t)c * GC * 50, qObj + (size_t)c * GC * 50,
                                         ln_g, ln_b, adjGc, X1c, 50, R);
    gemm_bt<<<dim3(R / 128, 6), 256, 0, stream>>>(X1c, gcnT1, nullptr, H2c, R, 768, 768);
    fused_l2<64><<<GC, 512, 0, stream>>>(adjGc, H2c, ln_g + 768, ln_b + 768,
                                         Xf + (size_t)c * GC * 768, 50, 1.f / 50.f,
                                         uv, cbuf, pF + (size_t)c * GC, qF + (size_t)c * GC);
  }

  // ---- frame-level graph (16 graphs of n=32) ----
  gemm_bt<<<dim3(4, 12), 256, 0, stream>>>(Xf, QHB, nullptr, QHf, 512, 1536, 768);
  fused_l1<32><<<16, 512, 0, stream>>>(QHf, Xf, pF, qF, ln_g, ln_b, adjFb, X1f, 32, 512);
  gemm_bt<<<dim3(4, 6), 256, 0, stream>>>(X1f, gcnT1, nullptr, H2f, 512, 768, 768);
  fused_l2<32><<<16, 512, 0, stream>>>(adjFb, H2f, ln_g + 768, ln_b + 768, Xm, 32, 1.f / 32.f,
                                       uv, cbuf, nullptr, nullptr);

  // ---- head ----
  concat_y<<<16, 384, 0, stream>>>(Xm, fgs, yout);
  fc1_relu<<<192, 256, 0, stream>>>(yout, fc1_w, fc1_b, hbuf);
  fc2_out<<<100, 256, 0, stream>>>(hbuf, fc2_w, fc2_b, out);
}